// Round 7
// baseline (718.031 us; speedup 1.0000x reference)
//
#include <hip/hip_runtime.h>
#include <hip/hip_bf16.h>
#include <math.h>

#define NEG_SLOPE 0.2f

typedef short bf16x8 __attribute__((ext_vector_type(8)));
typedef float f32x4 __attribute__((ext_vector_type(4)));

__device__ __forceinline__ float lrelu(float x){ return x >= 0.f ? x : NEG_SLOPE * x; }
__device__ __forceinline__ unsigned short f2bf(float f){
  __hip_bfloat16 h = __float2bfloat16(f);
  return *(unsigned short*)&h;
}
__device__ __forceinline__ float bf2f(unsigned short u){
  return __uint_as_float((unsigned)u << 16);
}
__device__ __forceinline__ void up8(uint4 q, float* f){
  f[0] = __uint_as_float(q.x << 16); f[1] = __uint_as_float(q.x & 0xffff0000u);
  f[2] = __uint_as_float(q.y << 16); f[3] = __uint_as_float(q.y & 0xffff0000u);
  f[4] = __uint_as_float(q.z << 16); f[5] = __uint_as_float(q.z & 0xffff0000u);
  f[6] = __uint_as_float(q.w << 16); f[7] = __uint_as_float(q.w & 0xffff0000u);
}

// async global->LDS, 16B per lane; lds dst = wave-uniform base + lane*16
__device__ __forceinline__ void gload_lds16(const unsigned short* g, unsigned short* l){
  __builtin_amdgcn_global_load_lds(
      (const __attribute__((address_space(1))) unsigned int*)g,
      (__attribute__((address_space(3))) unsigned int*)l, 16, 0, 0);
}

// ---- CSR construction ------------------------------------------------------
__global__ void k_deg(const int* __restrict__ ei, int* __restrict__ deg, int E){
  int e = blockIdx.x * 256 + threadIdx.x;
  if (e >= E) return;
  atomicAdd(&deg[ei[E + e]], 1);
}

// row width = deg[n] + 1 (self loop).  N = 16384 = 256 * 64, single block scan.
__global__ void k_scan(const int* __restrict__ deg, int* __restrict__ row_start, int N){
  __shared__ int s[256];
  int t = threadIdx.x;
  int base = t * 64;
  int sum = 0;
  for (int i = 0; i < 64; ++i) sum += deg[base + i] + 1;
  s[t] = sum;
  __syncthreads();
  for (int off = 1; off < 256; off <<= 1){
    int v = (t >= off) ? s[t - off] : 0;
    __syncthreads();
    s[t] += v;
    __syncthreads();
  }
  int run = s[t] - sum;   // exclusive
  for (int i = 0; i < 64; ++i){ row_start[base + i] = run; run += deg[base + i] + 1; }
  if (t == 255) row_start[N] = run;
}

// self slots (idx < N) + edge slots (idx >= N) in one launch
__global__ void k_csr_build(const int* __restrict__ ei, const int* __restrict__ row_start,
                            int* __restrict__ fill, int* __restrict__ csr_src,
                            int* __restrict__ csr_eid, int* __restrict__ csr_dst,
                            int N, int E){
  int idx = blockIdx.x * 256 + threadIdx.x;
  if (idx < N){
    int p = row_start[idx];
    csr_src[p] = idx;        // self loop in slot 0
    csr_eid[p] = E;          // sentinel
    csr_dst[p] = idx;
  } else {
    int e = idx - N;
    if (e >= E) return;
    int dst = ei[E + e];
    int p = row_start[dst] + 1 + atomicAdd(&fill[dst], 1);
    csr_src[p] = ei[e];
    csr_eid[p] = e;
    csr_dst[p] = dst;
  }
}

// merged: self-loop mean attr (first N*32 threads) + permuted bf16 copy (rest)
__global__ void k_eaprep(const float* __restrict__ ea, const int* __restrict__ csr_eid,
                         const int* __restrict__ row_start,
                         unsigned short* __restrict__ ea_perm, int N, int Eaug, int E){
  int idx = blockIdx.x * 256 + threadIdx.x;
  if (idx < N * 32){
    int n = idx >> 5, k = idx & 31;
    int rs = row_start[n], re = row_start[n + 1];
    float sum = 0.f;
    for (int i = rs + 1; i < re; ++i)
      sum += ea[(size_t)csr_eid[i] * 32 + k];
    float d = (float)max(re - rs - 1, 1);
    ea_perm[(size_t)rs * 32 + k] = f2bf(sum / d);
  } else {
    int j = idx - N * 32;
    int p = j >> 3, q = j & 7;
    if (p >= Eaug) return;
    int e = csr_eid[p];
    if (e >= E) return;   // self slot handled above
    float4 v = ((const float4*)(ea + (size_t)e * 32))[q];
    ushort4 o;
    o.x = f2bf(v.x); o.y = f2bf(v.y); o.z = f2bf(v.z); o.w = f2bf(v.w);
    *(ushort4*)&ea_perm[(size_t)p * 32 + q * 4] = o;
  }
}

// ---- dtype prep ------------------------------------------------------------
__global__ void k_cvt_bf16(const float* __restrict__ in, unsigned short* __restrict__ out, int n4){
  int idx = blockIdx.x * 256 + threadIdx.x;
  if (idx >= n4) return;
  float4 v = *(const float4*)&in[idx * 4];
  ushort4 o;
  o.x = f2bf(v.x); o.y = f2bf(v.y); o.z = f2bf(v.z); o.w = f2bf(v.w);
  *(ushort4*)&out[idx * 4] = o;
}

// ---- weight prep ------------------------------------------------------------
// W[K,N] fp32 -> Wt[N,K] bf16; blockIdx.z selects (W0->Wt0, W1->Wt1).
__global__ __launch_bounds__(256) void k_transpose2_bf16(const float* __restrict__ W0,
    const float* __restrict__ W1, unsigned short* __restrict__ Wt0,
    unsigned short* __restrict__ Wt1, int K, int N){
  __shared__ float tile[64][65];
  const float* W = blockIdx.z ? W1 : W0;
  unsigned short* Wt = blockIdx.z ? Wt1 : Wt0;
  int n0 = blockIdx.x * 64, k0 = blockIdx.y * 64;
  int col = threadIdx.x & 63, rq = threadIdx.x >> 6;
  #pragma unroll
  for (int i = 0; i < 16; ++i){
    int r = rq * 16 + i;
    tile[r][col] = W[(size_t)(k0 + r) * N + n0 + col];
  }
  __syncthreads();
  #pragma unroll
  for (int i = 0; i < 16; ++i){
    int r = rq * 16 + i;
    Wt[(size_t)(n0 + r) * K + k0 + col] = f2bf(tile[col][r]);
  }
}

__global__ void k_transpose_we(const float* __restrict__ We, unsigned short* __restrict__ WeT, int FO){
  int idx = blockIdx.x * 256 + threadIdx.x;
  if (idx >= 32 * FO) return;
  int k = idx / FO, n = idx % FO;
  WeT[n * 32 + k] = f2bf(We[idx]);
}

// ---- bf16 MFMA GEMM, dual-output (z: 0->L, 1->R), BK=64 split-half ---------
__global__ void k_mfma_gemm2(const unsigned short* __restrict__ A,
    const unsigned short* __restrict__ BtL, const unsigned short* __restrict__ BtR,
    const float* __restrict__ biasL, const float* __restrict__ biasR,
    unsigned short* __restrict__ CL, unsigned short* __restrict__ CR, int FO, int K){
  __shared__ unsigned short lds[16384];     // 32 KB: As0|As1|Bs0|Bs1 / C-tile
  unsigned short* As0 = lds;                // [128][32], K-half 0
  unsigned short* As1 = lds + 4096;         // [128][32], K-half 1
  unsigned short* Bs0 = lds + 8192;
  unsigned short* Bs1 = lds + 12288;
  const unsigned short* Bt = blockIdx.z ? BtR : BtL;
  const float* bias = blockIdx.z ? biasR : biasL;
  unsigned short* C = blockIdx.z ? CR : CL;
  int t = threadIdx.x;
  int mb = blockIdx.x, nb = blockIdx.y;
  int lane = t & 63, w = t >> 6;
  int wm = (w & 1) * 64, wn = (w >> 1) * 64;
  int lo = lane & 15, hi = lane >> 4;
  int srow = w * 32 + (lane >> 2);
  int scol = (lane & 3) * 8;                 // shorts
  const unsigned short* Ap0 = A + (size_t)(mb * 128 + srow) * K + scol;
  const unsigned short* Ap1 = Ap0 + (size_t)16 * K;
  const unsigned short* Bp0 = Bt + (size_t)(nb * 128 + srow) * K + scol;
  const unsigned short* Bp1 = Bp0 + (size_t)16 * K;
  unsigned short* Ad00 = As0 + (w * 32) * 32;       // wave-uniform LDS bases
  unsigned short* Ad01 = As0 + (w * 32 + 16) * 32;
  unsigned short* Ad10 = As1 + (w * 32) * 32;
  unsigned short* Ad11 = As1 + (w * 32 + 16) * 32;
  unsigned short* Bd00 = Bs0 + (w * 32) * 32;
  unsigned short* Bd01 = Bs0 + (w * 32 + 16) * 32;
  unsigned short* Bd10 = Bs1 + (w * 32) * 32;
  unsigned short* Bd11 = Bs1 + (w * 32 + 16) * 32;
  f32x4 acc[4][4] = {};
  for (int k0 = 0; k0 < K; k0 += 64){
    gload_lds16(Ap0 + k0, Ad00);
    gload_lds16(Ap1 + k0, Ad01);
    gload_lds16(Ap0 + k0 + 32, Ad10);
    gload_lds16(Ap1 + k0 + 32, Ad11);
    gload_lds16(Bp0 + k0, Bd00);
    gload_lds16(Bp1 + k0, Bd01);
    gload_lds16(Bp0 + k0 + 32, Bd10);
    gload_lds16(Bp1 + k0 + 32, Bd11);
    __syncthreads();
    #pragma unroll
    for (int ks = 0; ks < 2; ++ks){
      const unsigned short* Asx = ks ? As1 : As0;
      const unsigned short* Bsx = ks ? Bs1 : Bs0;
      bf16x8 af[4], bfr[4];
      #pragma unroll
      for (int i = 0; i < 4; ++i){
        af[i]  = *(const bf16x8*)&Asx[(wm + i * 16 + lo) * 32 + hi * 8];
        bfr[i] = *(const bf16x8*)&Bsx[(wn + i * 16 + lo) * 32 + hi * 8];
      }
      #pragma unroll
      for (int mi = 0; mi < 4; ++mi)
        #pragma unroll
        for (int ni = 0; ni < 4; ++ni)
          acc[mi][ni] = __builtin_amdgcn_mfma_f32_16x16x32_bf16(af[mi], bfr[ni], acc[mi][ni], 0, 0, 0);
    }
    __syncthreads();
  }
  // epilogue: acc -> LDS C-tile [128][128] shorts -> coalesced dwordx4 stores
  #pragma unroll
  for (int ni = 0; ni < 4; ++ni){
    int col = wn + ni * 16 + lo;
    float bv = bias[nb * 128 + col];
    #pragma unroll
    for (int mi = 0; mi < 4; ++mi){
      int row = wm + mi * 16 + hi * 4;
      #pragma unroll
      for (int r = 0; r < 4; ++r)
        lds[(row + r) * 128 + col] = f2bf(acc[mi][ni][r] + bv);
    }
  }
  __syncthreads();
  #pragma unroll
  for (int q = 0; q < 8; ++q){
    int idx = q * 256 + t;
    int row = idx >> 4;
    int cs = (idx & 15) * 8;
    *(float4*)&C[(size_t)(mb * 128 + row) * FO + nb * 128 + cs] = *(float4*)&lds[row * 128 + cs];
  }
}

// ---- fused EW-recompute + logit kernel (v8) --------------------------------
// v7 lesson: barrier-free free-running waves destroyed inter-wave cache
// coherence (FETCH +122MB) -> lockstep is a locality FEATURE.  v8 = v6's
// lockstep structure at half granularity: 64 CSR slots / 128 threads /
// 2 waves / ewt 17.5KB -> 8 resident blocks per CU (vs 2-3) hide each
// other's barrier drains while each block keeps the lockstep tile sweep.
template<int TILES>   // TILES = FO/128
__global__ __launch_bounds__(128, 4) void k_logit(const unsigned short* __restrict__ Ap,
    const unsigned short* __restrict__ WeT, const unsigned short* __restrict__ XL,
    const unsigned short* __restrict__ XRb, const int* __restrict__ csr_src,
    const int* __restrict__ csr_dst, const float* __restrict__ att,
    float* __restrict__ logit){
  const int FO = TILES * 128;
  const int EWS = 140;                       // padded row stride (shorts)
  __shared__ unsigned short ewt[64 * EWS];   // 17.5 KB EW tile (64 edges)
  __shared__ int s_soff[64], s_doff[64];
  int t = threadIdx.x;
  int base = blockIdx.x * 64;
  if (t < 64){
    s_soff[t] = csr_src[base + t] * FO;
    s_doff[t] = csr_dst[base + t] * FO;
  }
  int lane = t & 63, w = t >> 6;             // w in {0,1}
  int wn = w * 64;                           // this wave's 64 cols of each tile
  int lo = lane & 15, hi = lane >> 4;
  // A fragments (64 edge rows, K=32): invariant across col-tiles -> load once
  bf16x8 af[4];
  #pragma unroll
  for (int mi = 0; mi < 4; ++mi)
    af[mi] = *(const bf16x8*)&Ap[(size_t)(base + mi * 16 + lo) * 32 + hi * 8];
  int grp = t >> 4, li = t & 15;             // 8 groups x 8 edges
  __syncthreads();                           // publish s_soff/s_doff
  int soff8[8], doff8[8];
  #pragma unroll
  for (int e8 = 0; e8 < 8; ++e8){
    soff8[e8] = s_soff[grp * 8 + e8] + li * 8;
    doff8[e8] = s_doff[grp * 8 + e8] + li * 8;
  }
  float part[8] = {};
  #pragma unroll 1
  for (int nb = 0; nb < TILES; ++nb){
    // ---- MFMA phase: 64x64 strip per wave, drained per-ni (acc = 16 VGPRs)
    bf16x8 bfr[4];
    #pragma unroll
    for (int i = 0; i < 4; ++i)
      bfr[i] = *(const bf16x8*)&WeT[(size_t)(nb * 128 + wn + i * 16 + lo) * 32 + hi * 8];
    __syncthreads();   // prev consume done
    #pragma unroll
    for (int ni = 0; ni < 4; ++ni){
      f32x4 acc[4] = {};
      #pragma unroll
      for (int mi = 0; mi < 4; ++mi)
        acc[mi] = __builtin_amdgcn_mfma_f32_16x16x32_bf16(af[mi], bfr[ni], acc[mi], 0, 0, 0);
      int col = wn + ni * 16 + lo;
      #pragma unroll
      for (int mi = 0; mi < 4; ++mi){
        int row = mi * 16 + hi * 4;
        #pragma unroll
        for (int r = 0; r < 4; ++r)
          ewt[(row + r) * EWS + col] = f2bf(acc[mi][r]);
      }
    }
    __syncthreads();
    // ---- consume phase: 16-lane group per edge, vectorized row reads
    float4 aA = *(const float4*)&att[nb * 128 + li * 8];
    float4 aB = *(const float4*)&att[nb * 128 + li * 8 + 4];
    #pragma unroll
    for (int e8 = 0; e8 < 8; ++e8){
      int r = grp * 8 + e8;
      uint4 qx = *(const uint4*)&XL [(size_t)soff8[e8] + nb * 128];
      uint4 qr = *(const uint4*)&XRb[(size_t)doff8[e8] + nb * 128];
      uint4 qe = *(const uint4*)&ewt[r * EWS + li * 8];
      float fx[8], fr8[8], fe[8];
      up8(qx, fx); up8(qr, fr8); up8(qe, fe);
      float s;
      s  = aA.x * lrelu(fx[0] + fr8[0] + fe[0]);
      s += aA.y * lrelu(fx[1] + fr8[1] + fe[1]);
      s += aA.z * lrelu(fx[2] + fr8[2] + fe[2]);
      s += aA.w * lrelu(fx[3] + fr8[3] + fe[3]);
      s += aB.x * lrelu(fx[4] + fr8[4] + fe[4]);
      s += aB.y * lrelu(fx[5] + fr8[5] + fe[5]);
      s += aB.z * lrelu(fx[6] + fr8[6] + fe[6]);
      s += aB.w * lrelu(fx[7] + fr8[7] + fe[7]);
      part[e8] += s;
    }
  }
  // reduce partials across the 16 lanes of each group
  #pragma unroll
  for (int e8 = 0; e8 < 8; ++e8){
    float v = part[e8];
    v += __shfl_xor(v, 1, 64);
    v += __shfl_xor(v, 2, 64);
    v += __shfl_xor(v, 4, 64);
    v += __shfl_xor(v, 8, 64);
    if (li == 0) logit[base + grp * 8 + e8] = v;
  }
}

// ---- softmax + aggregation (one wave per dst node), logits precomputed -----
template<int CHUNKS, int VEC, typename OutT>
__global__ __launch_bounds__(256) void k_agg(const unsigned short* __restrict__ XL,
    const float* __restrict__ logit, const int* __restrict__ csr_src,
    const int* __restrict__ row_start, const float* __restrict__ bc,
    OutT* __restrict__ out){
  const int FO = CHUNKS * 64 * VEC;
  int lane = threadIdx.x & 63;
  int wave = threadIdx.x >> 6;
  int n = blockIdx.x * 4 + wave;
  int rs = row_start[n], re = row_start[n + 1];
  int jj = lane * VEC;
  float m = -1e30f;
  for (int i = rs; i < re; ++i) m = fmaxf(m, logit[i]);   // broadcast loads
  float acc[CHUNKS][VEC];
  #pragma unroll
  for (int c = 0; c < CHUNKS; ++c)
    #pragma unroll
    for (int v = 0; v < VEC; ++v) acc[c][v] = 0.f;
  float den = 0.f;
  int s_cur = csr_src[rs];
  float l_cur = logit[rs];
  for (int i = rs; i < re; ++i){
    float f = __expf(l_cur - m);
    int s = s_cur;
    if (i + 1 < re){ s_cur = csr_src[i + 1]; l_cur = logit[i + 1]; }  // break dep chain
    den += f;
    const unsigned short* xp = XL + (size_t)s * FO;
    #pragma unroll
    for (int c = 0; c < CHUNKS; ++c){
      int base = c * 64 * VEC + jj;
      float xl[VEC];
      if (VEC == 8){
        uint4 q = *(const uint4*)&xp[base];
        xl[0] = __uint_as_float(q.x << 16); xl[1] = __uint_as_float(q.x & 0xffff0000u);
        xl[2] = __uint_as_float(q.y << 16); xl[3] = __uint_as_float(q.y & 0xffff0000u);
        xl[4] = __uint_as_float(q.z << 16); xl[5] = __uint_as_float(q.z & 0xffff0000u);
        xl[6] = __uint_as_float(q.w << 16); xl[7] = __uint_as_float(q.w & 0xffff0000u);
      } else {
        ushort4 u = *(const ushort4*)&xp[base];
        xl[0] = bf2f(u.x); xl[1] = bf2f(u.y); xl[2] = bf2f(u.z); xl[3] = bf2f(u.w);
      }
      #pragma unroll
      for (int v = 0; v < VEC; ++v) acc[c][v] += f * xl[v];
    }
  }
  float inv = 1.f / den;
  #pragma unroll
  for (int c = 0; c < CHUNKS; ++c){
    int base = c * 64 * VEC + jj;
    #pragma unroll
    for (int v = 0; v < VEC; ++v){
      float b = bc[base + v];
      float o = fmaxf(acc[c][v] * inv + b, 0.f);
      if (sizeof(OutT) == 4) ((float*)out)[(size_t)n * FO + base + v] = o;
      else ((unsigned short*)out)[(size_t)n * FO + base + v] = f2bf(o);
    }
  }
}

// ---- pooling stage A: partial sums (graph g, part p of 8) ------------------
__global__ void k_pool_part(const float* __restrict__ H, const int* __restrict__ batch,
                            float* __restrict__ partial, int N){
  __shared__ int se[2];
  int g = blockIdx.x, part = blockIdx.y;
  int t = threadIdx.x;
  if (t < 2){
    int target = g + t;
    int lo = 0, hi = N;
    while (lo < hi){ int mid = (lo + hi) >> 1; if (batch[mid] < target) lo = mid + 1; else hi = mid; }
    se[t] = lo;
  }
  __syncthreads();
  int s = se[0], e = se[1];
  int len = e - s;
  int p0 = s + (int)((long)len * part / 8);
  int p1 = s + (int)((long)len * (part + 1) / 8);
  float a = 0.f;
  for (int n = p0; n < p1; ++n) a += H[(size_t)n * 256 + t];
  partial[((size_t)g * 8 + part) * 256 + t] = a;
}

// ---- pooling stage B: combine partials + fc1 -------------------------------
__global__ void k_fc1b(const float* __restrict__ partial, const int* __restrict__ batch,
                       const float* __restrict__ w, const float* __restrict__ b,
                       float* __restrict__ z, int N){
  __shared__ float ps[256];
  __shared__ int se[2];
  int g = blockIdx.x;
  int t = threadIdx.x;
  if (t < 2){
    int target = g + t;
    int lo = 0, hi = N;
    while (lo < hi){ int mid = (lo + hi) >> 1; if (batch[mid] < target) lo = mid + 1; else hi = mid; }
    se[t] = lo;
  }
  float a = 0.f;
  #pragma unroll
  for (int p = 0; p < 8; ++p) a += partial[((size_t)g * 8 + p) * 256 + t];
  ps[t] = a;
  __syncthreads();
  if (t < 64){
    float acc = 0.f;
    for (int k = 0; k < 256; ++k) acc += ps[k] * w[k * 64 + t];
    z[g * 64 + t] = acc / fmaxf((float)(se[1] - se[0]), 1.f) + b[t];
  }
}

__global__ void k_head(const float* __restrict__ z, const float* __restrict__ bn_g,
                       const float* __restrict__ bn_b, const float* __restrict__ w2,
                       const float* __restrict__ b2, float* __restrict__ out){
  __shared__ float mu_s[64], is_s[64];
  int t = threadIdx.x;  // 128 threads
  if (t < 64){
    float mu = 0.f, m2 = 0.f;
    for (int g = 0; g < 128; ++g){ float v = z[g * 64 + t]; mu += v; m2 += v * v; }
    mu /= 128.f; m2 /= 128.f;
    float var = m2 - mu * mu;
    mu_s[t] = mu;
    is_s[t] = rsqrtf(var + 1e-5f);
  }
  __syncthreads();
  float o = b2[0];
  for (int j = 0; j < 64; ++j){
    float v = (z[t * 64 + j] - mu_s[j]) * is_s[j] * bn_g[j] + bn_b[j];
    o += fmaxf(v, 0.f) * w2[j];
  }
  out[t] = o;
}

extern "C" void kernel_launch(void* const* d_in, const int* in_sizes, int n_in,
                              void* d_out, int out_size, void* d_ws, size_t ws_size,
                              hipStream_t stream){
  const int N = 16384, E = 131072, Eaug = E + N, NG = 128;
  const float* x     = (const float*)d_in[0];
  const int*   ei    = (const int*)  d_in[1];
  const float* ea    = (const float*)d_in[2];
  const int*   batch = (const int*)  d_in[3];
  const float* Wl[3]  = {(const float*)d_in[4],  (const float*)d_in[11], (const float*)d_in[18]};
  const float* bl[3]  = {(const float*)d_in[5],  (const float*)d_in[12], (const float*)d_in[19]};
  const float* Wr[3]  = {(const float*)d_in[6],  (const float*)d_in[13], (const float*)d_in[20]};
  const float* br[3]  = {(const float*)d_in[7],  (const float*)d_in[14], (const float*)d_in[21]};
  const float* We[3]  = {(const float*)d_in[8],  (const float*)d_in[15], (const float*)d_in[22]};
  const float* att[3] = {(const float*)d_in[9],  (const float*)d_in[16], (const float*)d_in[23]};
  const float* bc[3]  = {(const float*)d_in[10], (const float*)d_in[17], (const float*)d_in[24]};
  const float* fc1_w = (const float*)d_in[25];
  const float* fc1_b = (const float*)d_in[26];
  const float* bn_g  = (const float*)d_in[27];
  const float* bn_b  = (const float*)d_in[28];
  const float* fc2_w = (const float*)d_in[29];
  const float* fc2_b = (const float*)d_in[30];
  float* out = (float*)d_out;

  char* wsb = (char*)d_ws;
  size_t off = 0;
  auto alloc = [&](size_t bytes) -> char* {
    char* p = wsb + off;
    off = (off + bytes + 255) & ~(size_t)255;
    return p;
  };
  int*   deg       = (int*)  alloc((size_t)N * 4);
  int*   fill      = (int*)  alloc((size_t)N * 4);
  int*   row_start = (int*)  alloc((size_t)(N + 1) * 4);
  int*   csr_src   = (int*)  alloc((size_t)Eaug * 4);
  int*   csr_eid   = (int*)  alloc((size_t)Eaug * 4);
  int*   csr_dst   = (int*)  alloc((size_t)Eaug * 4);
  float* logits    = (float*)alloc((size_t)Eaug * 4);
  unsigned short* ea_perm = (unsigned short*)alloc((size_t)Eaug * 32 * 2);
  unsigned short* XL   = (unsigned short*)alloc((size_t)N * 1024 * 2); // 32 MB
  unsigned short* XRb  = (unsigned short*)alloc((size_t)N * 1024 * 2); // 32 MB
  unsigned short* bufA = (unsigned short*)alloc((size_t)N * 1024 * 2); // 32 MB: Xb / L2-out
  unsigned short* bufB = (unsigned short*)alloc((size_t)N * 512 * 4);  // 32 MB: L1-out bf16 / L3-out fp32
  unsigned short* WtL  = (unsigned short*)alloc((size_t)1024 * 1024 * 2);
  unsigned short* WtR  = (unsigned short*)alloc((size_t)1024 * 1024 * 2);
  unsigned short* WeT  = (unsigned short*)alloc((size_t)1024 * 32 * 2);
  float* ppart     = (float*)alloc((size_t)NG * 8 * 256 * 4);
  float* zbuf      = (float*)alloc((size_t)NG * 64 * 4);

  hipMemsetAsync(deg, 0, (size_t)2 * N * 4, stream);  // deg + fill (adjacent)

  k_deg<<<E / 256, 256, 0, stream>>>(ei, deg, E);
  k_scan<<<1, 256, 0, stream>>>(deg, row_start, N);
  k_csr_build<<<(N + E) / 256, 256, 0, stream>>>(ei, row_start, fill, csr_src, csr_eid, csr_dst, N, E);
  k_eaprep<<<(N * 32 + Eaug * 8 + 255) / 256, 256, 0, stream>>>(ea, csr_eid, row_start, ea_perm, N, Eaug, E);
  k_cvt_bf16<<<(N * 256 / 4) / 256, 256, 0, stream>>>(x, bufA, N * 256 / 4);  // Xb in bufA

  const int fin[3] = {256, 512, 1024};
  const int fo[3]  = {512, 1024, 256};
  const unsigned short* Ain[3] = {bufA, bufB, bufA};

  for (int L = 0; L < 3; ++L){
    int FI = fin[L], FO = fo[L];
    k_transpose2_bf16<<<dim3(FO / 64, FI / 64, 2), 256, 0, stream>>>(Wl[L], Wr[L], WtL, WtR, FI, FO);
    k_transpose_we<<<(32 * FO + 255) / 256, 256, 0, stream>>>(We[L], WeT, FO);
    dim3 gg(N / 128, FO / 128, 2);
    k_mfma_gemm2<<<gg, 256, 0, stream>>>(Ain[L], WtL, WtR, bl[L], br[L], XL, XRb, FO, FI);

    // one logit pass + one aggregation pass over the whole graph (no EW in HBM)
    if (FO == 512){
      k_logit<4><<<Eaug / 64, 128, 0, stream>>>(ea_perm, WeT, XL, XRb, csr_src, csr_dst, att[L], logits);
      k_agg<1, 8, unsigned short><<<N / 4, 256, 0, stream>>>(XL, logits, csr_src, row_start, bc[L], bufB);
    } else if (FO == 1024){
      k_logit<8><<<Eaug / 64, 128, 0, stream>>>(ea_perm, WeT, XL, XRb, csr_src, csr_dst, att[L], logits);
      k_agg<2, 8, unsigned short><<<N / 4, 256, 0, stream>>>(XL, logits, csr_src, row_start, bc[L], bufA);
    } else {
      k_logit<2><<<Eaug / 64, 128, 0, stream>>>(ea_perm, WeT, XL, XRb, csr_src, csr_dst, att[L], logits);
      k_agg<1, 4, float><<<N / 4, 256, 0, stream>>>(XL, logits, csr_src, row_start, bc[L], (float*)bufB);
    }
  }

  k_pool_part<<<dim3(NG, 8), 256, 0, stream>>>((const float*)bufB, batch, ppart, N);
  k_fc1b<<<NG, 256, 0, stream>>>(ppart, batch, fc1_w, fc1_b, zbuf, N);
  k_head<<<1, 128, 0, stream>>>(zbuf, bn_g, bn_b, fc2_w, fc2_b, out);
}

// Round 8
// 574.503 us; speedup vs baseline: 1.2498x; 1.2498x over previous
//
#include <hip/hip_runtime.h>
#include <hip/hip_bf16.h>
#include <math.h>

#define NEG_SLOPE 0.2f

typedef short bf16x8 __attribute__((ext_vector_type(8)));
typedef float f32x4 __attribute__((ext_vector_type(4)));

__device__ __forceinline__ float lrelu(float x){ return x >= 0.f ? x : NEG_SLOPE * x; }
__device__ __forceinline__ unsigned short f2bf(float f){
  __hip_bfloat16 h = __float2bfloat16(f);
  return *(unsigned short*)&h;
}
__device__ __forceinline__ float bf2f(unsigned short u){
  return __uint_as_float((unsigned)u << 16);
}
__device__ __forceinline__ void up8(uint4 q, float* f){
  f[0] = __uint_as_float(q.x << 16); f[1] = __uint_as_float(q.x & 0xffff0000u);
  f[2] = __uint_as_float(q.y << 16); f[3] = __uint_as_float(q.y & 0xffff0000u);
  f[4] = __uint_as_float(q.z << 16); f[5] = __uint_as_float(q.z & 0xffff0000u);
  f[6] = __uint_as_float(q.w << 16); f[7] = __uint_as_float(q.w & 0xffff0000u);
}

// async global->LDS, 16B per lane; lds dst = wave-uniform base + lane*16
__device__ __forceinline__ void gload_lds16(const unsigned short* g, unsigned short* l){
  __builtin_amdgcn_global_load_lds(
      (const __attribute__((address_space(1))) unsigned int*)g,
      (__attribute__((address_space(3))) unsigned int*)l, 16, 0, 0);
}

// ---- CSR construction ------------------------------------------------------
__global__ void k_deg(const int* __restrict__ ei, int* __restrict__ deg, int E){
  int e = blockIdx.x * 256 + threadIdx.x;
  if (e >= E) return;
  atomicAdd(&deg[ei[E + e]], 1);
}

// row width = deg[n] + 1 (self loop).  N = 16384 = 256 * 64, single block scan.
__global__ void k_scan(const int* __restrict__ deg, int* __restrict__ row_start, int N){
  __shared__ int s[256];
  int t = threadIdx.x;
  int base = t * 64;
  int sum = 0;
  for (int i = 0; i < 64; ++i) sum += deg[base + i] + 1;
  s[t] = sum;
  __syncthreads();
  for (int off = 1; off < 256; off <<= 1){
    int v = (t >= off) ? s[t - off] : 0;
    __syncthreads();
    s[t] += v;
    __syncthreads();
  }
  int run = s[t] - sum;   // exclusive
  for (int i = 0; i < 64; ++i){ row_start[base + i] = run; run += deg[base + i] + 1; }
  if (t == 255) row_start[N] = run;
}

// self slots (idx < N) + edge slots (idx >= N) in one launch
__global__ void k_csr_build(const int* __restrict__ ei, const int* __restrict__ row_start,
                            int* __restrict__ fill, int* __restrict__ csr_src,
                            int* __restrict__ csr_eid, int* __restrict__ csr_dst,
                            int N, int E){
  int idx = blockIdx.x * 256 + threadIdx.x;
  if (idx < N){
    int p = row_start[idx];
    csr_src[p] = idx;        // self loop in slot 0
    csr_eid[p] = E;          // sentinel
    csr_dst[p] = idx;
  } else {
    int e = idx - N;
    if (e >= E) return;
    int dst = ei[E + e];
    int p = row_start[dst] + 1 + atomicAdd(&fill[dst], 1);
    csr_src[p] = ei[e];
    csr_eid[p] = e;
    csr_dst[p] = dst;
  }
}

// merged: self-loop mean attr (first N*32 threads) + permuted bf16 copy (rest)
__global__ void k_eaprep(const float* __restrict__ ea, const int* __restrict__ csr_eid,
                         const int* __restrict__ row_start,
                         unsigned short* __restrict__ ea_perm, int N, int Eaug, int E){
  int idx = blockIdx.x * 256 + threadIdx.x;
  if (idx < N * 32){
    int n = idx >> 5, k = idx & 31;
    int rs = row_start[n], re = row_start[n + 1];
    float sum = 0.f;
    for (int i = rs + 1; i < re; ++i)
      sum += ea[(size_t)csr_eid[i] * 32 + k];
    float d = (float)max(re - rs - 1, 1);
    ea_perm[(size_t)rs * 32 + k] = f2bf(sum / d);
  } else {
    int j = idx - N * 32;
    int p = j >> 3, q = j & 7;
    if (p >= Eaug) return;
    int e = csr_eid[p];
    if (e >= E) return;   // self slot handled above
    float4 v = ((const float4*)(ea + (size_t)e * 32))[q];
    ushort4 o;
    o.x = f2bf(v.x); o.y = f2bf(v.y); o.z = f2bf(v.z); o.w = f2bf(v.w);
    *(ushort4*)&ea_perm[(size_t)p * 32 + q * 4] = o;
  }
}

// ---- dtype prep ------------------------------------------------------------
__global__ void k_cvt_bf16(const float* __restrict__ in, unsigned short* __restrict__ out, int n4){
  int idx = blockIdx.x * 256 + threadIdx.x;
  if (idx >= n4) return;
  float4 v = *(const float4*)&in[idx * 4];
  ushort4 o;
  o.x = f2bf(v.x); o.y = f2bf(v.y); o.z = f2bf(v.z); o.w = f2bf(v.w);
  *(ushort4*)&out[idx * 4] = o;
}

// ---- weight prep ------------------------------------------------------------
// W[K,N] fp32 -> Wt[N,K] bf16; blockIdx.z selects (W0->Wt0, W1->Wt1).
__global__ __launch_bounds__(256) void k_transpose2_bf16(const float* __restrict__ W0,
    const float* __restrict__ W1, unsigned short* __restrict__ Wt0,
    unsigned short* __restrict__ Wt1, int K, int N){
  __shared__ float tile[64][65];
  const float* W = blockIdx.z ? W1 : W0;
  unsigned short* Wt = blockIdx.z ? Wt1 : Wt0;
  int n0 = blockIdx.x * 64, k0 = blockIdx.y * 64;
  int col = threadIdx.x & 63, rq = threadIdx.x >> 6;
  #pragma unroll
  for (int i = 0; i < 16; ++i){
    int r = rq * 16 + i;
    tile[r][col] = W[(size_t)(k0 + r) * N + n0 + col];
  }
  __syncthreads();
  #pragma unroll
  for (int i = 0; i < 16; ++i){
    int r = rq * 16 + i;
    Wt[(size_t)(n0 + r) * K + k0 + col] = f2bf(tile[col][r]);
  }
}

__global__ void k_transpose_we(const float* __restrict__ We, unsigned short* __restrict__ WeT, int FO){
  int idx = blockIdx.x * 256 + threadIdx.x;
  if (idx >= 32 * FO) return;
  int k = idx / FO, n = idx % FO;
  WeT[n * 32 + k] = f2bf(We[idx]);
}

// ---- bf16 MFMA GEMM, dual-output (z: 0->L, 1->R), BK=64 split-half ---------
__global__ void k_mfma_gemm2(const unsigned short* __restrict__ A,
    const unsigned short* __restrict__ BtL, const unsigned short* __restrict__ BtR,
    const float* __restrict__ biasL, const float* __restrict__ biasR,
    unsigned short* __restrict__ CL, unsigned short* __restrict__ CR, int FO, int K){
  __shared__ unsigned short lds[16384];     // 32 KB: As0|As1|Bs0|Bs1 / C-tile
  unsigned short* As0 = lds;                // [128][32], K-half 0
  unsigned short* As1 = lds + 4096;         // [128][32], K-half 1
  unsigned short* Bs0 = lds + 8192;
  unsigned short* Bs1 = lds + 12288;
  const unsigned short* Bt = blockIdx.z ? BtR : BtL;
  const float* bias = blockIdx.z ? biasR : biasL;
  unsigned short* C = blockIdx.z ? CR : CL;
  int t = threadIdx.x;
  int mb = blockIdx.x, nb = blockIdx.y;
  int lane = t & 63, w = t >> 6;
  int wm = (w & 1) * 64, wn = (w >> 1) * 64;
  int lo = lane & 15, hi = lane >> 4;
  int srow = w * 32 + (lane >> 2);
  int scol = (lane & 3) * 8;                 // shorts
  const unsigned short* Ap0 = A + (size_t)(mb * 128 + srow) * K + scol;
  const unsigned short* Ap1 = Ap0 + (size_t)16 * K;
  const unsigned short* Bp0 = Bt + (size_t)(nb * 128 + srow) * K + scol;
  const unsigned short* Bp1 = Bp0 + (size_t)16 * K;
  unsigned short* Ad00 = As0 + (w * 32) * 32;       // wave-uniform LDS bases
  unsigned short* Ad01 = As0 + (w * 32 + 16) * 32;
  unsigned short* Ad10 = As1 + (w * 32) * 32;
  unsigned short* Ad11 = As1 + (w * 32 + 16) * 32;
  unsigned short* Bd00 = Bs0 + (w * 32) * 32;
  unsigned short* Bd01 = Bs0 + (w * 32 + 16) * 32;
  unsigned short* Bd10 = Bs1 + (w * 32) * 32;
  unsigned short* Bd11 = Bs1 + (w * 32 + 16) * 32;
  f32x4 acc[4][4] = {};
  for (int k0 = 0; k0 < K; k0 += 64){
    gload_lds16(Ap0 + k0, Ad00);
    gload_lds16(Ap1 + k0, Ad01);
    gload_lds16(Ap0 + k0 + 32, Ad10);
    gload_lds16(Ap1 + k0 + 32, Ad11);
    gload_lds16(Bp0 + k0, Bd00);
    gload_lds16(Bp1 + k0, Bd01);
    gload_lds16(Bp0 + k0 + 32, Bd10);
    gload_lds16(Bp1 + k0 + 32, Bd11);
    __syncthreads();
    #pragma unroll
    for (int ks = 0; ks < 2; ++ks){
      const unsigned short* Asx = ks ? As1 : As0;
      const unsigned short* Bsx = ks ? Bs1 : Bs0;
      bf16x8 af[4], bfr[4];
      #pragma unroll
      for (int i = 0; i < 4; ++i){
        af[i]  = *(const bf16x8*)&Asx[(wm + i * 16 + lo) * 32 + hi * 8];
        bfr[i] = *(const bf16x8*)&Bsx[(wn + i * 16 + lo) * 32 + hi * 8];
      }
      #pragma unroll
      for (int mi = 0; mi < 4; ++mi)
        #pragma unroll
        for (int ni = 0; ni < 4; ++ni)
          acc[mi][ni] = __builtin_amdgcn_mfma_f32_16x16x32_bf16(af[mi], bfr[ni], acc[mi][ni], 0, 0, 0);
    }
    __syncthreads();
  }
  // epilogue: acc -> LDS C-tile [128][128] shorts -> coalesced dwordx4 stores
  #pragma unroll
  for (int ni = 0; ni < 4; ++ni){
    int col = wn + ni * 16 + lo;
    float bv = bias[nb * 128 + col];
    #pragma unroll
    for (int mi = 0; mi < 4; ++mi){
      int row = wm + mi * 16 + hi * 4;
      #pragma unroll
      for (int r = 0; r < 4; ++r)
        lds[(row + r) * 128 + col] = f2bf(acc[mi][ni][r] + bv);
    }
  }
  __syncthreads();
  #pragma unroll
  for (int q = 0; q < 8; ++q){
    int idx = q * 256 + t;
    int row = idx >> 4;
    int cs = (idx & 15) * 8;
    *(float4*)&C[(size_t)(mb * 128 + row) * FO + nb * 128 + cs] = *(float4*)&lds[row * 128 + cs];
  }
}

// ---- fused EW-recompute + logit kernel (v9 = v6 + tile-split halves) -------
// v7/v8 lesson: the 128-slot/256-thread lockstep block is a cache-locality
// optimum -- keep its inner loop EXACTLY.  v9 splits the serial 8-tile chain
// across blockIdx.y in {0,1}: half y does tiles [y*T/2,(y+1)*T/2) and writes
// a private partial logit[y*Eaug + i].  2x blocks (better CU balance, half
// the per-block barrier chain); k_agg sums the two partials (exact: a+b).
template<int TILES>   // TILES = FO/128 (even)
__global__ __launch_bounds__(256, 3) void k_logit(const unsigned short* __restrict__ Ap,
    const unsigned short* __restrict__ WeT, const unsigned short* __restrict__ XL,
    const unsigned short* __restrict__ XRb, const int* __restrict__ csr_src,
    const int* __restrict__ csr_dst, const float* __restrict__ att,
    float* __restrict__ logit, int eaug){
  const int FO = TILES * 128;
  const int HT = TILES / 2;                   // tiles per half
  const int EWS = 140;                        // padded row stride (shorts)
  __shared__ unsigned short ewt[128 * EWS];   // 35 KB EW tile
  __shared__ int s_soff[128], s_doff[128];
  int t = threadIdx.x;
  int base = blockIdx.x * 128;
  int half = blockIdx.y;
  if (t < 128){
    s_soff[t] = csr_src[base + t] * FO;
    s_doff[t] = csr_dst[base + t] * FO;
  }
  int lane = t & 63, w = t >> 6;
  int wm = (w & 1) * 64, wn = (w >> 1) * 64;
  int lo = lane & 15, hi = lane >> 4;
  // A fragments (edge rows, K=32): invariant across col-tiles -> load once
  bf16x8 af[4];
  #pragma unroll
  for (int i = 0; i < 4; ++i)
    af[i] = *(const bf16x8*)&Ap[(size_t)(base + wm + i * 16 + lo) * 32 + hi * 8];
  int grp = t >> 4, li = t & 15;
  __syncthreads();           // publish s_soff/s_doff
  int soff8[8], doff8[8];
  #pragma unroll
  for (int e8 = 0; e8 < 8; ++e8){
    soff8[e8] = s_soff[grp * 8 + e8] + li * 8;
    doff8[e8] = s_doff[grp * 8 + e8] + li * 8;
  }
  float part[8] = {};
  #pragma unroll 1
  for (int nb = half * HT; nb < (half + 1) * HT; ++nb){
    // ---- MFMA phase: EW subtile, drained per-ni to keep VGPR low
    bf16x8 bfr[4];
    #pragma unroll
    for (int i = 0; i < 4; ++i)
      bfr[i] = *(const bf16x8*)&WeT[(size_t)(nb * 128 + wn + i * 16 + lo) * 32 + hi * 8];
    __syncthreads();   // prev consume done
    #pragma unroll
    for (int ni = 0; ni < 4; ++ni){
      f32x4 acc[4] = {};
      #pragma unroll
      for (int mi = 0; mi < 4; ++mi)
        acc[mi] = __builtin_amdgcn_mfma_f32_16x16x32_bf16(af[mi], bfr[ni], acc[mi], 0, 0, 0);
      int col = wn + ni * 16 + lo;
      #pragma unroll
      for (int mi = 0; mi < 4; ++mi){
        int row = wm + mi * 16 + hi * 4;
        #pragma unroll
        for (int r = 0; r < 4; ++r)
          ewt[(row + r) * EWS + col] = f2bf(acc[mi][r]);
      }
    }
    __syncthreads();
    // ---- consume phase: 16-lane group per edge, vectorized row reads
    float4 aA = *(const float4*)&att[nb * 128 + li * 8];
    float4 aB = *(const float4*)&att[nb * 128 + li * 8 + 4];
    #pragma unroll
    for (int e8 = 0; e8 < 8; ++e8){
      int r = grp * 8 + e8;
      uint4 qx = *(const uint4*)&XL [(size_t)soff8[e8] + nb * 128];
      uint4 qr = *(const uint4*)&XRb[(size_t)doff8[e8] + nb * 128];
      uint4 qe = *(const uint4*)&ewt[r * EWS + li * 8];
      float fx[8], fr8[8], fe[8];
      up8(qx, fx); up8(qr, fr8); up8(qe, fe);
      float s;
      s  = aA.x * lrelu(fx[0] + fr8[0] + fe[0]);
      s += aA.y * lrelu(fx[1] + fr8[1] + fe[1]);
      s += aA.z * lrelu(fx[2] + fr8[2] + fe[2]);
      s += aA.w * lrelu(fx[3] + fr8[3] + fe[3]);
      s += aB.x * lrelu(fx[4] + fr8[4] + fe[4]);
      s += aB.y * lrelu(fx[5] + fr8[5] + fe[5]);
      s += aB.z * lrelu(fx[6] + fr8[6] + fe[6]);
      s += aB.w * lrelu(fx[7] + fr8[7] + fe[7]);
      part[e8] += s;
    }
  }
  // reduce partials across the 16 lanes of each group
  #pragma unroll
  for (int e8 = 0; e8 < 8; ++e8){
    float v = part[e8];
    v += __shfl_xor(v, 1, 64);
    v += __shfl_xor(v, 2, 64);
    v += __shfl_xor(v, 4, 64);
    v += __shfl_xor(v, 8, 64);
    if (li == 0) logit[(size_t)half * eaug + base + grp * 8 + e8] = v;
  }
}

// ---- softmax + aggregation (one wave per dst node); logit = half0 + half1 --
template<int CHUNKS, int VEC, typename OutT>
__global__ __launch_bounds__(256) void k_agg(const unsigned short* __restrict__ XL,
    const float* __restrict__ logit, const int* __restrict__ csr_src,
    const int* __restrict__ row_start, const float* __restrict__ bc,
    OutT* __restrict__ out, int eaug){
  const int FO = CHUNKS * 64 * VEC;
  int lane = threadIdx.x & 63;
  int wave = threadIdx.x >> 6;
  int n = blockIdx.x * 4 + wave;
  int rs = row_start[n], re = row_start[n + 1];
  int jj = lane * VEC;
  float m = -1e30f;
  for (int i = rs; i < re; ++i) m = fmaxf(m, logit[i] + logit[eaug + i]);  // broadcast loads
  float acc[CHUNKS][VEC];
  #pragma unroll
  for (int c = 0; c < CHUNKS; ++c)
    #pragma unroll
    for (int v = 0; v < VEC; ++v) acc[c][v] = 0.f;
  float den = 0.f;
  int s_cur = csr_src[rs];
  float l_cur = logit[rs] + logit[eaug + rs];
  for (int i = rs; i < re; ++i){
    float f = __expf(l_cur - m);
    int s = s_cur;
    if (i + 1 < re){ s_cur = csr_src[i + 1]; l_cur = logit[i + 1] + logit[eaug + i + 1]; }
    den += f;
    const unsigned short* xp = XL + (size_t)s * FO;
    #pragma unroll
    for (int c = 0; c < CHUNKS; ++c){
      int base = c * 64 * VEC + jj;
      float xl[VEC];
      if (VEC == 8){
        uint4 q = *(const uint4*)&xp[base];
        xl[0] = __uint_as_float(q.x << 16); xl[1] = __uint_as_float(q.x & 0xffff0000u);
        xl[2] = __uint_as_float(q.y << 16); xl[3] = __uint_as_float(q.y & 0xffff0000u);
        xl[4] = __uint_as_float(q.z << 16); xl[5] = __uint_as_float(q.z & 0xffff0000u);
        xl[6] = __uint_as_float(q.w << 16); xl[7] = __uint_as_float(q.w & 0xffff0000u);
      } else {
        ushort4 u = *(const ushort4*)&xp[base];
        xl[0] = bf2f(u.x); xl[1] = bf2f(u.y); xl[2] = bf2f(u.z); xl[3] = bf2f(u.w);
      }
      #pragma unroll
      for (int v = 0; v < VEC; ++v) acc[c][v] += f * xl[v];
    }
  }
  float inv = 1.f / den;
  #pragma unroll
  for (int c = 0; c < CHUNKS; ++c){
    int base = c * 64 * VEC + jj;
    #pragma unroll
    for (int v = 0; v < VEC; ++v){
      float b = bc[base + v];
      float o = fmaxf(acc[c][v] * inv + b, 0.f);
      if (sizeof(OutT) == 4) ((float*)out)[(size_t)n * FO + base + v] = o;
      else ((unsigned short*)out)[(size_t)n * FO + base + v] = f2bf(o);
    }
  }
}

// ---- pooling stage A: partial sums (graph g, part p of 8) ------------------
__global__ void k_pool_part(const float* __restrict__ H, const int* __restrict__ batch,
                            float* __restrict__ partial, int N){
  __shared__ int se[2];
  int g = blockIdx.x, part = blockIdx.y;
  int t = threadIdx.x;
  if (t < 2){
    int target = g + t;
    int lo = 0, hi = N;
    while (lo < hi){ int mid = (lo + hi) >> 1; if (batch[mid] < target) lo = mid + 1; else hi = mid; }
    se[t] = lo;
  }
  __syncthreads();
  int s = se[0], e = se[1];
  int len = e - s;
  int p0 = s + (int)((long)len * part / 8);
  int p1 = s + (int)((long)len * (part + 1) / 8);
  float a = 0.f;
  for (int n = p0; n < p1; ++n) a += H[(size_t)n * 256 + t];
  partial[((size_t)g * 8 + part) * 256 + t] = a;
}

// ---- pooling stage B: combine partials + fc1 -------------------------------
__global__ void k_fc1b(const float* __restrict__ partial, const int* __restrict__ batch,
                       const float* __restrict__ w, const float* __restrict__ b,
                       float* __restrict__ z, int N){
  __shared__ float ps[256];
  __shared__ int se[2];
  int g = blockIdx.x;
  int t = threadIdx.x;
  if (t < 2){
    int target = g + t;
    int lo = 0, hi = N;
    while (lo < hi){ int mid = (lo + hi) >> 1; if (batch[mid] < target) lo = mid + 1; else hi = mid; }
    se[t] = lo;
  }
  float a = 0.f;
  #pragma unroll
  for (int p = 0; p < 8; ++p) a += partial[((size_t)g * 8 + p) * 256 + t];
  ps[t] = a;
  __syncthreads();
  if (t < 64){
    float acc = 0.f;
    for (int k = 0; k < 256; ++k) acc += ps[k] * w[k * 64 + t];
    z[g * 64 + t] = acc / fmaxf((float)(se[1] - se[0]), 1.f) + b[t];
  }
}

__global__ void k_head(const float* __restrict__ z, const float* __restrict__ bn_g,
                       const float* __restrict__ bn_b, const float* __restrict__ w2,
                       const float* __restrict__ b2, float* __restrict__ out){
  __shared__ float mu_s[64], is_s[64];
  int t = threadIdx.x;  // 128 threads
  if (t < 64){
    float mu = 0.f, m2 = 0.f;
    for (int g = 0; g < 128; ++g){ float v = z[g * 64 + t]; mu += v; m2 += v * v; }
    mu /= 128.f; m2 /= 128.f;
    float var = m2 - mu * mu;
    mu_s[t] = mu;
    is_s[t] = rsqrtf(var + 1e-5f);
  }
  __syncthreads();
  float o = b2[0];
  for (int j = 0; j < 64; ++j){
    float v = (z[t * 64 + j] - mu_s[j]) * is_s[j] * bn_g[j] + bn_b[j];
    o += fmaxf(v, 0.f) * w2[j];
  }
  out[t] = o;
}

extern "C" void kernel_launch(void* const* d_in, const int* in_sizes, int n_in,
                              void* d_out, int out_size, void* d_ws, size_t ws_size,
                              hipStream_t stream){
  const int N = 16384, E = 131072, Eaug = E + N, NG = 128;
  const float* x     = (const float*)d_in[0];
  const int*   ei    = (const int*)  d_in[1];
  const float* ea    = (const float*)d_in[2];
  const int*   batch = (const int*)  d_in[3];
  const float* Wl[3]  = {(const float*)d_in[4],  (const float*)d_in[11], (const float*)d_in[18]};
  const float* bl[3]  = {(const float*)d_in[5],  (const float*)d_in[12], (const float*)d_in[19]};
  const float* Wr[3]  = {(const float*)d_in[6],  (const float*)d_in[13], (const float*)d_in[20]};
  const float* br[3]  = {(const float*)d_in[7],  (const float*)d_in[14], (const float*)d_in[21]};
  const float* We[3]  = {(const float*)d_in[8],  (const float*)d_in[15], (const float*)d_in[22]};
  const float* att[3] = {(const float*)d_in[9],  (const float*)d_in[16], (const float*)d_in[23]};
  const float* bc[3]  = {(const float*)d_in[10], (const float*)d_in[17], (const float*)d_in[24]};
  const float* fc1_w = (const float*)d_in[25];
  const float* fc1_b = (const float*)d_in[26];
  const float* bn_g  = (const float*)d_in[27];
  const float* bn_b  = (const float*)d_in[28];
  const float* fc2_w = (const float*)d_in[29];
  const float* fc2_b = (const float*)d_in[30];
  float* out = (float*)d_out;

  char* wsb = (char*)d_ws;
  size_t off = 0;
  auto alloc = [&](size_t bytes) -> char* {
    char* p = wsb + off;
    off = (off + bytes + 255) & ~(size_t)255;
    return p;
  };
  int*   deg       = (int*)  alloc((size_t)N * 4);
  int*   fill      = (int*)  alloc((size_t)N * 4);
  int*   row_start = (int*)  alloc((size_t)(N + 1) * 4);
  int*   csr_src   = (int*)  alloc((size_t)Eaug * 4);
  int*   csr_eid   = (int*)  alloc((size_t)Eaug * 4);
  int*   csr_dst   = (int*)  alloc((size_t)Eaug * 4);
  float* logits    = (float*)alloc((size_t)2 * Eaug * 4);   // two tile-half partials
  unsigned short* ea_perm = (unsigned short*)alloc((size_t)Eaug * 32 * 2);
  unsigned short* XL   = (unsigned short*)alloc((size_t)N * 1024 * 2); // 32 MB
  unsigned short* XRb  = (unsigned short*)alloc((size_t)N * 1024 * 2); // 32 MB
  unsigned short* bufA = (unsigned short*)alloc((size_t)N * 1024 * 2); // 32 MB: Xb / L2-out
  unsigned short* bufB = (unsigned short*)alloc((size_t)N * 512 * 4);  // 32 MB: L1-out bf16 / L3-out fp32
  unsigned short* WtL  = (unsigned short*)alloc((size_t)1024 * 1024 * 2);
  unsigned short* WtR  = (unsigned short*)alloc((size_t)1024 * 1024 * 2);
  unsigned short* WeT  = (unsigned short*)alloc((size_t)1024 * 32 * 2);
  float* ppart     = (float*)alloc((size_t)NG * 8 * 256 * 4);
  float* zbuf      = (float*)alloc((size_t)NG * 64 * 4);

  hipMemsetAsync(deg, 0, (size_t)2 * N * 4, stream);  // deg + fill (adjacent)

  k_deg<<<E / 256, 256, 0, stream>>>(ei, deg, E);
  k_scan<<<1, 256, 0, stream>>>(deg, row_start, N);
  k_csr_build<<<(N + E) / 256, 256, 0, stream>>>(ei, row_start, fill, csr_src, csr_eid, csr_dst, N, E);
  k_eaprep<<<(N * 32 + Eaug * 8 + 255) / 256, 256, 0, stream>>>(ea, csr_eid, row_start, ea_perm, N, Eaug, E);
  k_cvt_bf16<<<(N * 256 / 4) / 256, 256, 0, stream>>>(x, bufA, N * 256 / 4);  // Xb in bufA

  const int fin[3] = {256, 512, 1024};
  const int fo[3]  = {512, 1024, 256};
  const unsigned short* Ain[3] = {bufA, bufB, bufA};

  for (int L = 0; L < 3; ++L){
    int FI = fin[L], FO = fo[L];
    k_transpose2_bf16<<<dim3(FO / 64, FI / 64, 2), 256, 0, stream>>>(Wl[L], Wr[L], WtL, WtR, FI, FO);
    k_transpose_we<<<(32 * FO + 255) / 256, 256, 0, stream>>>(We[L], WeT, FO);
    dim3 gg(N / 128, FO / 128, 2);
    k_mfma_gemm2<<<gg, 256, 0, stream>>>(Ain[L], WtL, WtR, bl[L], br[L], XL, XRb, FO, FI);

    // one logit pass (2 tile-half blocks per 128 slots) + one aggregation pass
    dim3 lg(Eaug / 128, 2);
    if (FO == 512){
      k_logit<4><<<lg, 256, 0, stream>>>(ea_perm, WeT, XL, XRb, csr_src, csr_dst, att[L], logits, Eaug);
      k_agg<1, 8, unsigned short><<<N / 4, 256, 0, stream>>>(XL, logits, csr_src, row_start, bc[L], bufB, Eaug);
    } else if (FO == 1024){
      k_logit<8><<<lg, 256, 0, stream>>>(ea_perm, WeT, XL, XRb, csr_src, csr_dst, att[L], logits, Eaug);
      k_agg<2, 8, unsigned short><<<N / 4, 256, 0, stream>>>(XL, logits, csr_src, row_start, bc[L], bufA, Eaug);
    } else {
      k_logit<2><<<lg, 256, 0, stream>>>(ea_perm, WeT, XL, XRb, csr_src, csr_dst, att[L], logits, Eaug);
      k_agg<1, 4, float><<<N / 4, 256, 0, stream>>>(XL, logits, csr_src, row_start, bc[L], (float*)bufB, Eaug);
    }
  }

  k_pool_part<<<dim3(NG, 8), 256, 0, stream>>>((const float*)bufB, batch, ppart, N);
  k_fc1b<<<NG, 256, 0, stream>>>(ppart, batch, fc1_w, fc1_b, zbuf, N);
  k_head<<<1, 128, 0, stream>>>(zbuf, bn_g, bn_b, fc2_w, fc2_b, out);
}

// Round 10
// 560.107 us; speedup vs baseline: 1.2820x; 1.0257x over previous
//
#include <hip/hip_runtime.h>
#include <hip/hip_bf16.h>
#include <math.h>

#define NEG_SLOPE 0.2f

typedef short bf16x8 __attribute__((ext_vector_type(8)));
typedef float f32x4 __attribute__((ext_vector_type(4)));

__device__ __forceinline__ float lrelu(float x){ return x >= 0.f ? x : NEG_SLOPE * x; }
__device__ __forceinline__ unsigned short f2bf(float f){
  __hip_bfloat16 h = __float2bfloat16(f);
  return *(unsigned short*)&h;
}
__device__ __forceinline__ float bf2f(unsigned short u){
  return __uint_as_float((unsigned)u << 16);
}
__device__ __forceinline__ void up8(uint4 q, float* f){
  f[0] = __uint_as_float(q.x << 16); f[1] = __uint_as_float(q.x & 0xffff0000u);
  f[2] = __uint_as_float(q.y << 16); f[3] = __uint_as_float(q.y & 0xffff0000u);
  f[4] = __uint_as_float(q.z << 16); f[5] = __uint_as_float(q.z & 0xffff0000u);
  f[6] = __uint_as_float(q.w << 16); f[7] = __uint_as_float(q.w & 0xffff0000u);
}

// async global->LDS, 16B per lane; lds dst = wave-uniform base + lane*16
__device__ __forceinline__ void gload_lds16(const unsigned short* g, unsigned short* l){
  __builtin_amdgcn_global_load_lds(
      (const __attribute__((address_space(1))) unsigned int*)g,
      (__attribute__((address_space(3))) unsigned int*)l, 16, 0, 0);
}

// ---- CSR construction ------------------------------------------------------
__global__ void k_deg(const int* __restrict__ ei, int* __restrict__ deg, int E){
  int e = blockIdx.x * 256 + threadIdx.x;
  if (e >= E) return;
  atomicAdd(&deg[ei[E + e]], 1);
}

// row width = deg[n] + 1 (self loop).  N = 16384 = 256 * 64, single block scan.
__global__ void k_scan(const int* __restrict__ deg, int* __restrict__ row_start, int N){
  __shared__ int s[256];
  int t = threadIdx.x;
  int base = t * 64;
  int sum = 0;
  for (int i = 0; i < 64; ++i) sum += deg[base + i] + 1;
  s[t] = sum;
  __syncthreads();
  for (int off = 1; off < 256; off <<= 1){
    int v = (t >= off) ? s[t - off] : 0;
    __syncthreads();
    s[t] += v;
    __syncthreads();
  }
  int run = s[t] - sum;   // exclusive
  for (int i = 0; i < 64; ++i){ row_start[base + i] = run; run += deg[base + i] + 1; }
  if (t == 255) row_start[N] = run;
}

// self slots (idx < N) + edge slots (idx >= N) in one launch
__global__ void k_csr_build(const int* __restrict__ ei, const int* __restrict__ row_start,
                            int* __restrict__ fill, int* __restrict__ csr_src,
                            int* __restrict__ csr_eid, int* __restrict__ csr_dst,
                            int N, int E){
  int idx = blockIdx.x * 256 + threadIdx.x;
  if (idx < N){
    int p = row_start[idx];
    csr_src[p] = idx;        // self loop in slot 0
    csr_eid[p] = E;          // sentinel
    csr_dst[p] = idx;
  } else {
    int e = idx - N;
    if (e >= E) return;
    int dst = ei[E + e];
    int p = row_start[dst] + 1 + atomicAdd(&fill[dst], 1);
    csr_src[p] = ei[e];
    csr_eid[p] = e;
    csr_dst[p] = dst;
  }
}

// merged: self-loop mean attr (first N*32 threads) + permuted bf16 copy (rest)
__global__ void k_eaprep(const float* __restrict__ ea, const int* __restrict__ csr_eid,
                         const int* __restrict__ row_start,
                         unsigned short* __restrict__ ea_perm, int N, int Eaug, int E){
  int idx = blockIdx.x * 256 + threadIdx.x;
  if (idx < N * 32){
    int n = idx >> 5, k = idx & 31;
    int rs = row_start[n], re = row_start[n + 1];
    float sum = 0.f;
    for (int i = rs + 1; i < re; ++i)
      sum += ea[(size_t)csr_eid[i] * 32 + k];
    float d = (float)max(re - rs - 1, 1);
    ea_perm[(size_t)rs * 32 + k] = f2bf(sum / d);
  } else {
    int j = idx - N * 32;
    int p = j >> 3, q = j & 7;
    if (p >= Eaug) return;
    int e = csr_eid[p];
    if (e >= E) return;   // self slot handled above
    float4 v = ((const float4*)(ea + (size_t)e * 32))[q];
    ushort4 o;
    o.x = f2bf(v.x); o.y = f2bf(v.y); o.z = f2bf(v.z); o.w = f2bf(v.w);
    *(ushort4*)&ea_perm[(size_t)p * 32 + q * 4] = o;
  }
}

// ---- dtype prep ------------------------------------------------------------
__global__ void k_cvt_bf16(const float* __restrict__ in, unsigned short* __restrict__ out, int n4){
  int idx = blockIdx.x * 256 + threadIdx.x;
  if (idx >= n4) return;
  float4 v = *(const float4*)&in[idx * 4];
  ushort4 o;
  o.x = f2bf(v.x); o.y = f2bf(v.y); o.z = f2bf(v.z); o.w = f2bf(v.w);
  *(ushort4*)&out[idx * 4] = o;
}

// ---- weight prep ------------------------------------------------------------
// W[K,N] fp32 -> Wt[N,K] bf16; blockIdx.z selects (W0->Wt0, W1->Wt1).
__global__ __launch_bounds__(256) void k_transpose2_bf16(const float* __restrict__ W0,
    const float* __restrict__ W1, unsigned short* __restrict__ Wt0,
    unsigned short* __restrict__ Wt1, int K, int N){
  __shared__ float tile[64][65];
  const float* W = blockIdx.z ? W1 : W0;
  unsigned short* Wt = blockIdx.z ? Wt1 : Wt0;
  int n0 = blockIdx.x * 64, k0 = blockIdx.y * 64;
  int col = threadIdx.x & 63, rq = threadIdx.x >> 6;
  #pragma unroll
  for (int i = 0; i < 16; ++i){
    int r = rq * 16 + i;
    tile[r][col] = W[(size_t)(k0 + r) * N + n0 + col];
  }
  __syncthreads();
  #pragma unroll
  for (int i = 0; i < 16; ++i){
    int r = rq * 16 + i;
    Wt[(size_t)(n0 + r) * K + k0 + col] = f2bf(tile[col][r]);
  }
}

__global__ void k_transpose_we(const float* __restrict__ We, unsigned short* __restrict__ WeT, int FO){
  int idx = blockIdx.x * 256 + threadIdx.x;
  if (idx >= 32 * FO) return;
  int k = idx / FO, n = idx % FO;
  WeT[n * 32 + k] = f2bf(We[idx]);
}

// ---- bf16 MFMA GEMM, dual-output (z: 0->L, 1->R), BK=64 split-half ---------
// v10: XCD-aware chunked swizzle on blockIdx.x (T1): each XCD keeps a
// contiguous 16-M-tile A-panel in its private L2.  gridDim.x=128, %8==0.
__global__ void k_mfma_gemm2(const unsigned short* __restrict__ A,
    const unsigned short* __restrict__ BtL, const unsigned short* __restrict__ BtR,
    const float* __restrict__ biasL, const float* __restrict__ biasR,
    unsigned short* __restrict__ CL, unsigned short* __restrict__ CR, int FO, int K){
  __shared__ unsigned short lds[16384];     // 32 KB: As0|As1|Bs0|Bs1 / C-tile
  unsigned short* As0 = lds;                // [128][32], K-half 0
  unsigned short* As1 = lds + 4096;         // [128][32], K-half 1
  unsigned short* Bs0 = lds + 8192;
  unsigned short* Bs1 = lds + 12288;
  const unsigned short* Bt = blockIdx.z ? BtR : BtL;
  const float* bias = blockIdx.z ? biasR : biasL;
  unsigned short* C = blockIdx.z ? CR : CL;
  int t = threadIdx.x;
  int bx = blockIdx.x;
  int cpx = gridDim.x >> 3;                  // chunks per XCD (16)
  int mb = (bx & 7) * cpx + (bx >> 3);       // bijective XCD swizzle
  int nb = blockIdx.y;
  int lane = t & 63, w = t >> 6;
  int wm = (w & 1) * 64, wn = (w >> 1) * 64;
  int lo = lane & 15, hi = lane >> 4;
  int srow = w * 32 + (lane >> 2);
  int scol = (lane & 3) * 8;                 // shorts
  const unsigned short* Ap0 = A + (size_t)(mb * 128 + srow) * K + scol;
  const unsigned short* Ap1 = Ap0 + (size_t)16 * K;
  const unsigned short* Bp0 = Bt + (size_t)(nb * 128 + srow) * K + scol;
  const unsigned short* Bp1 = Bp0 + (size_t)16 * K;
  unsigned short* Ad00 = As0 + (w * 32) * 32;       // wave-uniform LDS bases
  unsigned short* Ad01 = As0 + (w * 32 + 16) * 32;
  unsigned short* Ad10 = As1 + (w * 32) * 32;
  unsigned short* Ad11 = As1 + (w * 32 + 16) * 32;
  unsigned short* Bd00 = Bs0 + (w * 32) * 32;
  unsigned short* Bd01 = Bs0 + (w * 32 + 16) * 32;
  unsigned short* Bd10 = Bs1 + (w * 32) * 32;
  unsigned short* Bd11 = Bs1 + (w * 32 + 16) * 32;
  f32x4 acc[4][4] = {};
  for (int k0 = 0; k0 < K; k0 += 64){
    gload_lds16(Ap0 + k0, Ad00);
    gload_lds16(Ap1 + k0, Ad01);
    gload_lds16(Ap0 + k0 + 32, Ad10);
    gload_lds16(Ap1 + k0 + 32, Ad11);
    gload_lds16(Bp0 + k0, Bd00);
    gload_lds16(Bp1 + k0, Bd01);
    gload_lds16(Bp0 + k0 + 32, Bd10);
    gload_lds16(Bp1 + k0 + 32, Bd11);
    __syncthreads();
    #pragma unroll
    for (int ks = 0; ks < 2; ++ks){
      const unsigned short* Asx = ks ? As1 : As0;
      const unsigned short* Bsx = ks ? Bs1 : Bs0;
      bf16x8 af[4], bfr[4];
      #pragma unroll
      for (int i = 0; i < 4; ++i){
        af[i]  = *(const bf16x8*)&Asx[(wm + i * 16 + lo) * 32 + hi * 8];
        bfr[i] = *(const bf16x8*)&Bsx[(wn + i * 16 + lo) * 32 + hi * 8];
      }
      #pragma unroll
      for (int mi = 0; mi < 4; ++mi)
        #pragma unroll
        for (int ni = 0; ni < 4; ++ni)
          acc[mi][ni] = __builtin_amdgcn_mfma_f32_16x16x32_bf16(af[mi], bfr[ni], acc[mi][ni], 0, 0, 0);
    }
    __syncthreads();
  }
  // epilogue: acc -> LDS C-tile [128][128] shorts -> coalesced dwordx4 stores
  #pragma unroll
  for (int ni = 0; ni < 4; ++ni){
    int col = wn + ni * 16 + lo;
    float bv = bias[nb * 128 + col];
    #pragma unroll
    for (int mi = 0; mi < 4; ++mi){
      int row = wm + mi * 16 + hi * 4;
      #pragma unroll
      for (int r = 0; r < 4; ++r)
        lds[(row + r) * 128 + col] = f2bf(acc[mi][ni][r] + bv);
    }
  }
  __syncthreads();
  #pragma unroll
  for (int q = 0; q < 8; ++q){
    int idx = q * 256 + t;
    int row = idx >> 4;
    int cs = (idx & 15) * 8;
    *(float4*)&C[(size_t)(mb * 128 + row) * FO + nb * 128 + cs] = *(float4*)&lds[row * 128 + cs];
  }
}

// ---- fused EW-recompute + logit kernel (v9 = v6 + tile-split halves) -------
template<int TILES>   // TILES = FO/128 (even)
__global__ __launch_bounds__(256, 3) void k_logit(const unsigned short* __restrict__ Ap,
    const unsigned short* __restrict__ WeT, const unsigned short* __restrict__ XL,
    const unsigned short* __restrict__ XRb, const int* __restrict__ csr_src,
    const int* __restrict__ csr_dst, const float* __restrict__ att,
    float* __restrict__ logit, int eaug){
  const int FO = TILES * 128;
  const int HT = TILES / 2;                   // tiles per half
  const int EWS = 140;                        // padded row stride (shorts)
  __shared__ unsigned short ewt[128 * EWS];   // 35 KB EW tile
  __shared__ int s_soff[128], s_doff[128];
  int t = threadIdx.x;
  int base = blockIdx.x * 128;
  int half = blockIdx.y;
  if (t < 128){
    s_soff[t] = csr_src[base + t] * FO;
    s_doff[t] = csr_dst[base + t] * FO;
  }
  int lane = t & 63, w = t >> 6;
  int wm = (w & 1) * 64, wn = (w >> 1) * 64;
  int lo = lane & 15, hi = lane >> 4;
  // A fragments (edge rows, K=32): invariant across col-tiles -> load once
  bf16x8 af[4];
  #pragma unroll
  for (int i = 0; i < 4; ++i)
    af[i] = *(const bf16x8*)&Ap[(size_t)(base + wm + i * 16 + lo) * 32 + hi * 8];
  int grp = t >> 4, li = t & 15;
  __syncthreads();           // publish s_soff/s_doff
  int soff8[8], doff8[8];
  #pragma unroll
  for (int e8 = 0; e8 < 8; ++e8){
    soff8[e8] = s_soff[grp * 8 + e8] + li * 8;
    doff8[e8] = s_doff[grp * 8 + e8] + li * 8;
  }
  float part[8] = {};
  #pragma unroll 1
  for (int nb = half * HT; nb < (half + 1) * HT; ++nb){
    // ---- MFMA phase: EW subtile, drained per-ni to keep VGPR low
    bf16x8 bfr[4];
    #pragma unroll
    for (int i = 0; i < 4; ++i)
      bfr[i] = *(const bf16x8*)&WeT[(size_t)(nb * 128 + wn + i * 16 + lo) * 32 + hi * 8];
    __syncthreads();   // prev consume done
    #pragma unroll
    for (int ni = 0; ni < 4; ++ni){
      f32x4 acc[4] = {};
      #pragma unroll
      for (int mi = 0; mi < 4; ++mi)
        acc[mi] = __builtin_amdgcn_mfma_f32_16x16x32_bf16(af[mi], bfr[ni], acc[mi], 0, 0, 0);
      int col = wn + ni * 16 + lo;
      #pragma unroll
      for (int mi = 0; mi < 4; ++mi){
        int row = wm + mi * 16 + hi * 4;
        #pragma unroll
        for (int r = 0; r < 4; ++r)
          ewt[(row + r) * EWS + col] = f2bf(acc[mi][r]);
      }
    }
    __syncthreads();
    // ---- consume phase: 16-lane group per edge, vectorized row reads
    float4 aA = *(const float4*)&att[nb * 128 + li * 8];
    float4 aB = *(const float4*)&att[nb * 128 + li * 8 + 4];
    #pragma unroll
    for (int e8 = 0; e8 < 8; ++e8){
      int r = grp * 8 + e8;
      uint4 qx = *(const uint4*)&XL [(size_t)soff8[e8] + nb * 128];
      uint4 qr = *(const uint4*)&XRb[(size_t)doff8[e8] + nb * 128];
      uint4 qe = *(const uint4*)&ewt[r * EWS + li * 8];
      float fx[8], fr8[8], fe[8];
      up8(qx, fx); up8(qr, fr8); up8(qe, fe);
      float s;
      s  = aA.x * lrelu(fx[0] + fr8[0] + fe[0]);
      s += aA.y * lrelu(fx[1] + fr8[1] + fe[1]);
      s += aA.z * lrelu(fx[2] + fr8[2] + fe[2]);
      s += aA.w * lrelu(fx[3] + fr8[3] + fe[3]);
      s += aB.x * lrelu(fx[4] + fr8[4] + fe[4]);
      s += aB.y * lrelu(fx[5] + fr8[5] + fe[5]);
      s += aB.z * lrelu(fx[6] + fr8[6] + fe[6]);
      s += aB.w * lrelu(fx[7] + fr8[7] + fe[7]);
      part[e8] += s;
    }
  }
  // reduce partials across the 16 lanes of each group
  #pragma unroll
  for (int e8 = 0; e8 < 8; ++e8){
    float v = part[e8];
    v += __shfl_xor(v, 1, 64);
    v += __shfl_xor(v, 2, 64);
    v += __shfl_xor(v, 4, 64);
    v += __shfl_xor(v, 8, 64);
    if (li == 0) logit[(size_t)half * eaug + base + grp * 8 + e8] = v;
  }
}

// ---- softmax + aggregation (one wave per dst node); logit = half0 + half1 --
// v10: 2-edge unroll (2x memory-level parallelism in the latency-bound edge
// loop); blockIdx.y column-split (CW cols per block) for FO=1024.
template<int CHUNKS, int VEC, typename OutT>
__global__ __launch_bounds__(256) void k_agg(const unsigned short* __restrict__ XL,
    const float* __restrict__ logit, const int* __restrict__ csr_src,
    const int* __restrict__ row_start, const float* __restrict__ bc,
    OutT* __restrict__ out, int eaug, int FO){
  const int CW = CHUNKS * 64 * VEC;          // columns handled by this block
  int col0 = blockIdx.y * CW;
  int lane = threadIdx.x & 63;
  int wave = threadIdx.x >> 6;
  int n = blockIdx.x * 4 + wave;
  int rs = row_start[n], re = row_start[n + 1];
  int jj = lane * VEC;
  float m = -1e30f;
  for (int i = rs; i < re; ++i) m = fmaxf(m, logit[i] + logit[eaug + i]);  // broadcast
  float acc[CHUNKS][VEC];
  #pragma unroll
  for (int c = 0; c < CHUNKS; ++c)
    #pragma unroll
    for (int v = 0; v < VEC; ++v) acc[c][v] = 0.f;
  float den = 0.f;
  int i = rs;
  for (; i + 1 < re; i += 2){
    int s0 = csr_src[i], s1 = csr_src[i + 1];
    float f0 = __expf(logit[i] + logit[eaug + i] - m);
    float f1 = __expf(logit[i + 1] + logit[eaug + i + 1] - m);
    const unsigned short* xp0 = XL + (size_t)s0 * FO + col0 + jj;
    const unsigned short* xp1 = XL + (size_t)s1 * FO + col0 + jj;
    den += f0 + f1;
    #pragma unroll
    for (int c = 0; c < CHUNKS; ++c){
      float xl0[VEC], xl1[VEC];
      if (VEC == 8){
        uint4 q0 = *(const uint4*)(xp0 + c * 64 * VEC);
        uint4 q1 = *(const uint4*)(xp1 + c * 64 * VEC);
        up8(q0, xl0); up8(q1, xl1);
      } else {
        ushort4 u0 = *(const ushort4*)(xp0 + c * 64 * VEC);
        ushort4 u1 = *(const ushort4*)(xp1 + c * 64 * VEC);
        xl0[0] = bf2f(u0.x); xl0[1] = bf2f(u0.y); xl0[2] = bf2f(u0.z); xl0[3] = bf2f(u0.w);
        xl1[0] = bf2f(u1.x); xl1[1] = bf2f(u1.y); xl1[2] = bf2f(u1.z); xl1[3] = bf2f(u1.w);
      }
      #pragma unroll
      for (int v = 0; v < VEC; ++v) acc[c][v] += f0 * xl0[v] + f1 * xl1[v];
    }
  }
  if (i < re){
    int s0 = csr_src[i];
    float f0 = __expf(logit[i] + logit[eaug + i] - m);
    const unsigned short* xp0 = XL + (size_t)s0 * FO + col0 + jj;
    den += f0;
    #pragma unroll
    for (int c = 0; c < CHUNKS; ++c){
      float xl0[VEC];
      if (VEC == 8){
        uint4 q0 = *(const uint4*)(xp0 + c * 64 * VEC);
        up8(q0, xl0);
      } else {
        ushort4 u0 = *(const ushort4*)(xp0 + c * 64 * VEC);
        xl0[0] = bf2f(u0.x); xl0[1] = bf2f(u0.y); xl0[2] = bf2f(u0.z); xl0[3] = bf2f(u0.w);
      }
      #pragma unroll
      for (int v = 0; v < VEC; ++v) acc[c][v] += f0 * xl0[v];
    }
  }
  float inv = 1.f / den;
  #pragma unroll
  for (int c = 0; c < CHUNKS; ++c){
    int cb = col0 + c * 64 * VEC + jj;
    #pragma unroll
    for (int v = 0; v < VEC; ++v){
      float b = bc[cb + v];
      float o = fmaxf(acc[c][v] * inv + b, 0.f);
      if (sizeof(OutT) == 4) ((float*)out)[(size_t)n * FO + cb + v] = o;
      else ((unsigned short*)out)[(size_t)n * FO + cb + v] = f2bf(o);
    }
  }
}

// ---- pooling stage A: partial sums (graph g, part p of 8) ------------------
__global__ void k_pool_part(const float* __restrict__ H, const int* __restrict__ batch,
                            float* __restrict__ partial, int N){
  __shared__ int se[2];
  int g = blockIdx.x, part = blockIdx.y;
  int t = threadIdx.x;
  if (t < 2){
    int target = g + t;
    int lo = 0, hi = N;
    while (lo < hi){ int mid = (lo + hi) >> 1; if (batch[mid] < target) lo = mid + 1; else hi = mid; }
    se[t] = lo;
  }
  __syncthreads();
  int s = se[0], e = se[1];
  int len = e - s;
  int p0 = s + (int)((long)len * part / 8);
  int p1 = s + (int)((long)len * (part + 1) / 8);
  float a = 0.f;
  for (int n = p0; n < p1; ++n) a += H[(size_t)n * 256 + t];
  partial[((size_t)g * 8 + part) * 256 + t] = a;
}

// ---- pooling stage B: combine partials + fc1 -------------------------------
__global__ void k_fc1b(const float* __restrict__ partial, const int* __restrict__ batch,
                       const float* __restrict__ w, const float* __restrict__ b,
                       float* __restrict__ z, int N){
  __shared__ float ps[256];
  __shared__ int se[2];
  int g = blockIdx.x;
  int t = threadIdx.x;
  if (t < 2){
    int target = g + t;
    int lo = 0, hi = N;
    while (lo < hi){ int mid = (lo + hi) >> 1; if (batch[mid] < target) lo = mid + 1; else hi = mid; }
    se[t] = lo;
  }
  float a = 0.f;
  #pragma unroll
  for (int p = 0; p < 8; ++p) a += partial[((size_t)g * 8 + p) * 256 + t];
  ps[t] = a;
  __syncthreads();
  if (t < 64){
    float acc = 0.f;
    for (int k = 0; k < 256; ++k) acc += ps[k] * w[k * 64 + t];
    z[g * 64 + t] = acc / fmaxf((float)(se[1] - se[0]), 1.f) + b[t];
  }
}

__global__ void k_head(const float* __restrict__ z, const float* __restrict__ bn_g,
                       const float* __restrict__ bn_b, const float* __restrict__ w2,
                       const float* __restrict__ b2, float* __restrict__ out){
  __shared__ float mu_s[64], is_s[64];
  int t = threadIdx.x;  // 128 threads
  if (t < 64){
    float mu = 0.f, m2 = 0.f;
    for (int g = 0; g < 128; ++g){ float v = z[g * 64 + t]; mu += v; m2 += v * v; }
    mu /= 128.f; m2 /= 128.f;
    float var = m2 - mu * mu;
    mu_s[t] = mu;
    is_s[t] = rsqrtf(var + 1e-5f);
  }
  __syncthreads();
  float o = b2[0];
  for (int j = 0; j < 64; ++j){
    float v = (z[t * 64 + j] - mu_s[j]) * is_s[j] * bn_g[j] + bn_b[j];
    o += fmaxf(v, 0.f) * w2[j];
  }
  out[t] = o;
}

extern "C" void kernel_launch(void* const* d_in, const int* in_sizes, int n_in,
                              void* d_out, int out_size, void* d_ws, size_t ws_size,
                              hipStream_t stream){
  const int N = 16384, E = 131072, Eaug = E + N, NG = 128;
  const float* x     = (const float*)d_in[0];
  const int*   ei    = (const int*)  d_in[1];
  const float* ea    = (const float*)d_in[2];
  const int*   batch = (const int*)  d_in[3];
  const float* Wl[3]  = {(const float*)d_in[4],  (const float*)d_in[11], (const float*)d_in[18]};
  const float* bl[3]  = {(const float*)d_in[5],  (const float*)d_in[12], (const float*)d_in[19]};
  const float* Wr[3]  = {(const float*)d_in[6],  (const float*)d_in[13], (const float*)d_in[20]};
  const float* br[3]  = {(const float*)d_in[7],  (const float*)d_in[14], (const float*)d_in[21]};
  const float* We[3]  = {(const float*)d_in[8],  (const float*)d_in[15], (const float*)d_in[22]};
  const float* att[3] = {(const float*)d_in[9],  (const float*)d_in[16], (const float*)d_in[23]};
  const float* bc[3]  = {(const float*)d_in[10], (const float*)d_in[17], (const float*)d_in[24]};
  const float* fc1_w = (const float*)d_in[25];
  const float* fc1_b = (const float*)d_in[26];
  const float* bn_g  = (const float*)d_in[27];
  const float* bn_b  = (const float*)d_in[28];
  const float* fc2_w = (const float*)d_in[29];
  const float* fc2_b = (const float*)d_in[30];
  float* out = (float*)d_out;

  char* wsb = (char*)d_ws;
  size_t off = 0;
  auto alloc = [&](size_t bytes) -> char* {
    char* p = wsb + off;
    off = (off + bytes + 255) & ~(size_t)255;
    return p;
  };
  int*   deg       = (int*)  alloc((size_t)N * 4);
  int*   fill      = (int*)  alloc((size_t)N * 4);
  int*   row_start = (int*)  alloc((size_t)(N + 1) * 4);
  int*   csr_src   = (int*)  alloc((size_t)Eaug * 4);
  int*   csr_eid   = (int*)  alloc((size_t)Eaug * 4);
  int*   csr_dst   = (int*)  alloc((size_t)Eaug * 4);
  float* logits    = (float*)alloc((size_t)2 * Eaug * 4);   // two tile-half partials
  unsigned short* ea_perm = (unsigned short*)alloc((size_t)Eaug * 32 * 2);
  unsigned short* XL   = (unsigned short*)alloc((size_t)N * 1024 * 2); // 32 MB
  unsigned short* XRb  = (unsigned short*)alloc((size_t)N * 1024 * 2); // 32 MB
  unsigned short* bufA = (unsigned short*)alloc((size_t)N * 1024 * 2); // 32 MB: Xb / L2-out
  unsigned short* bufB = (unsigned short*)alloc((size_t)N * 512 * 4);  // 32 MB: L1-out bf16 / L3-out fp32
  unsigned short* WtL  = (unsigned short*)alloc((size_t)1024 * 1024 * 2);
  unsigned short* WtR  = (unsigned short*)alloc((size_t)1024 * 1024 * 2);
  unsigned short* WeT  = (unsigned short*)alloc((size_t)1024 * 32 * 2);
  float* ppart     = (float*)alloc((size_t)NG * 8 * 256 * 4);
  float* zbuf      = (float*)alloc((size_t)NG * 64 * 4);

  hipMemsetAsync(deg, 0, (size_t)2 * N * 4, stream);  // deg + fill (adjacent)

  k_deg<<<E / 256, 256, 0, stream>>>(ei, deg, E);
  k_scan<<<1, 256, 0, stream>>>(deg, row_start, N);
  k_csr_build<<<(N + E) / 256, 256, 0, stream>>>(ei, row_start, fill, csr_src, csr_eid, csr_dst, N, E);
  k_eaprep<<<(N * 32 + Eaug * 8 + 255) / 256, 256, 0, stream>>>(ea, csr_eid, row_start, ea_perm, N, Eaug, E);
  k_cvt_bf16<<<(N * 256 / 4) / 256, 256, 0, stream>>>(x, bufA, N * 256 / 4);  // Xb in bufA

  const int fin[3] = {256, 512, 1024};
  const int fo[3]  = {512, 1024, 256};
  const unsigned short* Ain[3] = {bufA, bufB, bufA};

  for (int L = 0; L < 3; ++L){
    int FI = fin[L], FO = fo[L];
    k_transpose2_bf16<<<dim3(FO / 64, FI / 64, 2), 256, 0, stream>>>(Wl[L], Wr[L], WtL, WtR, FI, FO);
    k_transpose_we<<<(32 * FO + 255) / 256, 256, 0, stream>>>(We[L], WeT, FO);
    dim3 gg(N / 128, FO / 128, 2);
    k_mfma_gemm2<<<gg, 256, 0, stream>>>(Ain[L], WtL, WtR, bl[L], br[L], XL, XRb, FO, FI);

    // one logit pass (2 tile-half blocks per 128 slots) + one aggregation pass
    dim3 lg(Eaug / 128, 2);
    if (FO == 512){
      k_logit<4><<<lg, 256, 0, stream>>>(ea_perm, WeT, XL, XRb, csr_src, csr_dst, att[L], logits, Eaug);
      k_agg<1, 8, unsigned short><<<dim3(N / 4, 1), 256, 0, stream>>>(XL, logits, csr_src, row_start, bc[L], bufB, Eaug, 512);
    } else if (FO == 1024){
      k_logit<8><<<lg, 256, 0, stream>>>(ea_perm, WeT, XL, XRb, csr_src, csr_dst, att[L], logits, Eaug);
      k_agg<1, 8, unsigned short><<<dim3(N / 4, 2), 256, 0, stream>>>(XL, logits, csr_src, row_start, bc[L], bufA, Eaug, 1024);
    } else {
      k_logit<2><<<lg, 256, 0, stream>>>(ea_perm, WeT, XL, XRb, csr_src, csr_dst, att[L], logits, Eaug);
      k_agg<1, 4, float><<<dim3(N / 4, 1), 256, 0, stream>>>(XL, logits, csr_src, row_start, bc[L], (float*)bufB, Eaug, 256);
    }
  }

  k_pool_part<<<dim3(NG, 8), 256, 0, stream>>>((const float*)bufB, batch, ppart, N);
  k_fc1b<<<NG, 256, 0, stream>>>(ppart, batch, fc1_w, fc1_b, zbuf, N);
  k_head<<<1, 128, 0, stream>>>(zbuf, bn_g, bn_b, fc2_w, fc2_b, out);
}

// Round 11
// 507.318 us; speedup vs baseline: 1.4153x; 1.1041x over previous
//
#include <hip/hip_runtime.h>
#include <hip/hip_bf16.h>
#include <math.h>

#define NEG_SLOPE 0.2f

typedef short bf16x8 __attribute__((ext_vector_type(8)));
typedef float f32x4 __attribute__((ext_vector_type(4)));

// lrelu(x) == fmaxf(x, 0.2x) for all finite x: 2 VALU ops vs 3 (cmp+mul+cndmask)
__device__ __forceinline__ float lrelu(float x){ return fmaxf(x, NEG_SLOPE * x); }
__device__ __forceinline__ unsigned short f2bf(float f){
  __hip_bfloat16 h = __float2bfloat16(f);
  return *(unsigned short*)&h;
}
__device__ __forceinline__ float bf2f(unsigned short u){
  return __uint_as_float((unsigned)u << 16);
}
__device__ __forceinline__ void up8(uint4 q, float* f){
  f[0] = __uint_as_float(q.x << 16); f[1] = __uint_as_float(q.x & 0xffff0000u);
  f[2] = __uint_as_float(q.y << 16); f[3] = __uint_as_float(q.y & 0xffff0000u);
  f[4] = __uint_as_float(q.z << 16); f[5] = __uint_as_float(q.z & 0xffff0000u);
  f[6] = __uint_as_float(q.w << 16); f[7] = __uint_as_float(q.w & 0xffff0000u);
}

// async global->LDS, 16B per lane; lds dst = wave-uniform base + lane*16
__device__ __forceinline__ void gload_lds16(const unsigned short* g, unsigned short* l){
  __builtin_amdgcn_global_load_lds(
      (const __attribute__((address_space(1))) unsigned int*)g,
      (__attribute__((address_space(3))) unsigned int*)l, 16, 0, 0);
}

// ---- CSR construction ------------------------------------------------------
__global__ void k_deg(const int* __restrict__ ei, int* __restrict__ deg, int E){
  int e = blockIdx.x * 256 + threadIdx.x;
  if (e >= E) return;
  atomicAdd(&deg[ei[E + e]], 1);
}

// row width = deg[n] + 1 (self loop).  N = 16384 = 256 * 64, single block scan.
__global__ void k_scan(const int* __restrict__ deg, int* __restrict__ row_start, int N){
  __shared__ int s[256];
  int t = threadIdx.x;
  int base = t * 64;
  int sum = 0;
  for (int i = 0; i < 64; ++i) sum += deg[base + i] + 1;
  s[t] = sum;
  __syncthreads();
  for (int off = 1; off < 256; off <<= 1){
    int v = (t >= off) ? s[t - off] : 0;
    __syncthreads();
    s[t] += v;
    __syncthreads();
  }
  int run = s[t] - sum;   // exclusive
  for (int i = 0; i < 64; ++i){ row_start[base + i] = run; run += deg[base + i] + 1; }
  if (t == 255) row_start[N] = run;
}

// self slots (idx < N) + edge slots (idx >= N) in one launch
__global__ void k_csr_build(const int* __restrict__ ei, const int* __restrict__ row_start,
                            int* __restrict__ fill, int* __restrict__ csr_src,
                            int* __restrict__ csr_eid, int* __restrict__ csr_dst,
                            int N, int E){
  int idx = blockIdx.x * 256 + threadIdx.x;
  if (idx < N){
    int p = row_start[idx];
    csr_src[p] = idx;        // self loop in slot 0
    csr_eid[p] = E;          // sentinel
    csr_dst[p] = idx;
  } else {
    int e = idx - N;
    if (e >= E) return;
    int dst = ei[E + e];
    int p = row_start[dst] + 1 + atomicAdd(&fill[dst], 1);
    csr_src[p] = ei[e];
    csr_eid[p] = e;
    csr_dst[p] = dst;
  }
}

// merged: self-loop mean attr (first N*32 threads) + permuted bf16 copy (rest)
__global__ void k_eaprep(const float* __restrict__ ea, const int* __restrict__ csr_eid,
                         const int* __restrict__ row_start,
                         unsigned short* __restrict__ ea_perm, int N, int Eaug, int E){
  int idx = blockIdx.x * 256 + threadIdx.x;
  if (idx < N * 32){
    int n = idx >> 5, k = idx & 31;
    int rs = row_start[n], re = row_start[n + 1];
    float sum = 0.f;
    for (int i = rs + 1; i < re; ++i)
      sum += ea[(size_t)csr_eid[i] * 32 + k];
    float d = (float)max(re - rs - 1, 1);
    ea_perm[(size_t)rs * 32 + k] = f2bf(sum / d);
  } else {
    int j = idx - N * 32;
    int p = j >> 3, q = j & 7;
    if (p >= Eaug) return;
    int e = csr_eid[p];
    if (e >= E) return;   // self slot handled above
    float4 v = ((const float4*)(ea + (size_t)e * 32))[q];
    ushort4 o;
    o.x = f2bf(v.x); o.y = f2bf(v.y); o.z = f2bf(v.z); o.w = f2bf(v.w);
    *(ushort4*)&ea_perm[(size_t)p * 32 + q * 4] = o;
  }
}

// ---- dtype prep ------------------------------------------------------------
__global__ void k_cvt_bf16(const float* __restrict__ in, unsigned short* __restrict__ out, int n4){
  int idx = blockIdx.x * 256 + threadIdx.x;
  if (idx >= n4) return;
  float4 v = *(const float4*)&in[idx * 4];
  ushort4 o;
  o.x = f2bf(v.x); o.y = f2bf(v.y); o.z = f2bf(v.z); o.w = f2bf(v.w);
  *(ushort4*)&out[idx * 4] = o;
}

// ---- weight prep ------------------------------------------------------------
// W[K,N] fp32 -> Wt[N,K] bf16; blockIdx.z selects (W0->Wt0, W1->Wt1).
__global__ __launch_bounds__(256) void k_transpose2_bf16(const float* __restrict__ W0,
    const float* __restrict__ W1, unsigned short* __restrict__ Wt0,
    unsigned short* __restrict__ Wt1, int K, int N){
  __shared__ float tile[64][65];
  const float* W = blockIdx.z ? W1 : W0;
  unsigned short* Wt = blockIdx.z ? Wt1 : Wt0;
  int n0 = blockIdx.x * 64, k0 = blockIdx.y * 64;
  int col = threadIdx.x & 63, rq = threadIdx.x >> 6;
  #pragma unroll
  for (int i = 0; i < 16; ++i){
    int r = rq * 16 + i;
    tile[r][col] = W[(size_t)(k0 + r) * N + n0 + col];
  }
  __syncthreads();
  #pragma unroll
  for (int i = 0; i < 16; ++i){
    int r = rq * 16 + i;
    Wt[(size_t)(n0 + r) * K + k0 + col] = f2bf(tile[col][r]);
  }
}

__global__ void k_transpose_we(const float* __restrict__ We, unsigned short* __restrict__ WeT, int FO){
  int idx = blockIdx.x * 256 + threadIdx.x;
  if (idx >= 32 * FO) return;
  int k = idx / FO, n = idx % FO;
  WeT[n * 32 + k] = f2bf(We[idx]);
}

// ---- bf16 MFMA GEMM, dual-output (z: 0->L, 1->R), BK=64 split-half ---------
// XCD-aware chunked swizzle on blockIdx.x (T1).  gridDim.x=128, %8==0.
__global__ void k_mfma_gemm2(const unsigned short* __restrict__ A,
    const unsigned short* __restrict__ BtL, const unsigned short* __restrict__ BtR,
    const float* __restrict__ biasL, const float* __restrict__ biasR,
    unsigned short* __restrict__ CL, unsigned short* __restrict__ CR, int FO, int K){
  __shared__ unsigned short lds[16384];     // 32 KB: As0|As1|Bs0|Bs1 / C-tile
  unsigned short* As0 = lds;                // [128][32], K-half 0
  unsigned short* As1 = lds + 4096;         // [128][32], K-half 1
  unsigned short* Bs0 = lds + 8192;
  unsigned short* Bs1 = lds + 12288;
  const unsigned short* Bt = blockIdx.z ? BtR : BtL;
  const float* bias = blockIdx.z ? biasR : biasL;
  unsigned short* C = blockIdx.z ? CR : CL;
  int t = threadIdx.x;
  int bx = blockIdx.x;
  int cpx = gridDim.x >> 3;                  // chunks per XCD (16)
  int mb = (bx & 7) * cpx + (bx >> 3);       // bijective XCD swizzle
  int nb = blockIdx.y;
  int lane = t & 63, w = t >> 6;
  int wm = (w & 1) * 64, wn = (w >> 1) * 64;
  int lo = lane & 15, hi = lane >> 4;
  int srow = w * 32 + (lane >> 2);
  int scol = (lane & 3) * 8;                 // shorts
  const unsigned short* Ap0 = A + (size_t)(mb * 128 + srow) * K + scol;
  const unsigned short* Ap1 = Ap0 + (size_t)16 * K;
  const unsigned short* Bp0 = Bt + (size_t)(nb * 128 + srow) * K + scol;
  const unsigned short* Bp1 = Bp0 + (size_t)16 * K;
  unsigned short* Ad00 = As0 + (w * 32) * 32;       // wave-uniform LDS bases
  unsigned short* Ad01 = As0 + (w * 32 + 16) * 32;
  unsigned short* Ad10 = As1 + (w * 32) * 32;
  unsigned short* Ad11 = As1 + (w * 32 + 16) * 32;
  unsigned short* Bd00 = Bs0 + (w * 32) * 32;
  unsigned short* Bd01 = Bs0 + (w * 32 + 16) * 32;
  unsigned short* Bd10 = Bs1 + (w * 32) * 32;
  unsigned short* Bd11 = Bs1 + (w * 32 + 16) * 32;
  f32x4 acc[4][4] = {};
  for (int k0 = 0; k0 < K; k0 += 64){
    gload_lds16(Ap0 + k0, Ad00);
    gload_lds16(Ap1 + k0, Ad01);
    gload_lds16(Ap0 + k0 + 32, Ad10);
    gload_lds16(Ap1 + k0 + 32, Ad11);
    gload_lds16(Bp0 + k0, Bd00);
    gload_lds16(Bp1 + k0, Bd01);
    gload_lds16(Bp0 + k0 + 32, Bd10);
    gload_lds16(Bp1 + k0 + 32, Bd11);
    __syncthreads();
    #pragma unroll
    for (int ks = 0; ks < 2; ++ks){
      const unsigned short* Asx = ks ? As1 : As0;
      const unsigned short* Bsx = ks ? Bs1 : Bs0;
      bf16x8 af[4], bfr[4];
      #pragma unroll
      for (int i = 0; i < 4; ++i){
        af[i]  = *(const bf16x8*)&Asx[(wm + i * 16 + lo) * 32 + hi * 8];
        bfr[i] = *(const bf16x8*)&Bsx[(wn + i * 16 + lo) * 32 + hi * 8];
      }
      #pragma unroll
      for (int mi = 0; mi < 4; ++mi)
        #pragma unroll
        for (int ni = 0; ni < 4; ++ni)
          acc[mi][ni] = __builtin_amdgcn_mfma_f32_16x16x32_bf16(af[mi], bfr[ni], acc[mi][ni], 0, 0, 0);
    }
    __syncthreads();
  }
  // epilogue: acc -> LDS C-tile [128][128] shorts -> coalesced dwordx4 stores
  #pragma unroll
  for (int ni = 0; ni < 4; ++ni){
    int col = wn + ni * 16 + lo;
    float bv = bias[nb * 128 + col];
    #pragma unroll
    for (int mi = 0; mi < 4; ++mi){
      int row = wm + mi * 16 + hi * 4;
      #pragma unroll
      for (int r = 0; r < 4; ++r)
        lds[(row + r) * 128 + col] = f2bf(acc[mi][ni][r] + bv);
    }
  }
  __syncthreads();
  #pragma unroll
  for (int q = 0; q < 8; ++q){
    int idx = q * 256 + t;
    int row = idx >> 4;
    int cs = (idx & 15) * 8;
    *(float4*)&C[(size_t)(mb * 128 + row) * FO + nb * 128 + cs] = *(float4*)&lds[row * 128 + cs];
  }
}

// ---- fused EW-recompute + logit kernel (v9 structure, unchanged) -----------
template<int TILES>   // TILES = FO/128 (even)
__global__ __launch_bounds__(256, 3) void k_logit(const unsigned short* __restrict__ Ap,
    const unsigned short* __restrict__ WeT, const unsigned short* __restrict__ XL,
    const unsigned short* __restrict__ XRb, const int* __restrict__ csr_src,
    const int* __restrict__ csr_dst, const float* __restrict__ att,
    float* __restrict__ logit, int eaug){
  const int FO = TILES * 128;
  const int HT = TILES / 2;                   // tiles per half
  const int EWS = 140;                        // padded row stride (shorts)
  __shared__ unsigned short ewt[128 * EWS];   // 35 KB EW tile
  __shared__ int s_soff[128], s_doff[128];
  int t = threadIdx.x;
  int base = blockIdx.x * 128;
  int half = blockIdx.y;
  if (t < 128){
    s_soff[t] = csr_src[base + t] * FO;
    s_doff[t] = csr_dst[base + t] * FO;
  }
  int lane = t & 63, w = t >> 6;
  int wm = (w & 1) * 64, wn = (w >> 1) * 64;
  int lo = lane & 15, hi = lane >> 4;
  // A fragments (edge rows, K=32): invariant across col-tiles -> load once
  bf16x8 af[4];
  #pragma unroll
  for (int i = 0; i < 4; ++i)
    af[i] = *(const bf16x8*)&Ap[(size_t)(base + wm + i * 16 + lo) * 32 + hi * 8];
  int grp = t >> 4, li = t & 15;
  __syncthreads();           // publish s_soff/s_doff
  int soff8[8], doff8[8];
  #pragma unroll
  for (int e8 = 0; e8 < 8; ++e8){
    soff8[e8] = s_soff[grp * 8 + e8] + li * 8;
    doff8[e8] = s_doff[grp * 8 + e8] + li * 8;
  }
  float part[8] = {};
  #pragma unroll 1
  for (int nb = half * HT; nb < (half + 1) * HT; ++nb){
    // ---- MFMA phase: EW subtile, drained per-ni to keep VGPR low
    bf16x8 bfr[4];
    #pragma unroll
    for (int i = 0; i < 4; ++i)
      bfr[i] = *(const bf16x8*)&WeT[(size_t)(nb * 128 + wn + i * 16 + lo) * 32 + hi * 8];
    __syncthreads();   // prev consume done
    #pragma unroll
    for (int ni = 0; ni < 4; ++ni){
      f32x4 acc[4] = {};
      #pragma unroll
      for (int mi = 0; mi < 4; ++mi)
        acc[mi] = __builtin_amdgcn_mfma_f32_16x16x32_bf16(af[mi], bfr[ni], acc[mi], 0, 0, 0);
      int col = wn + ni * 16 + lo;
      #pragma unroll
      for (int mi = 0; mi < 4; ++mi){
        int row = wm + mi * 16 + hi * 4;
        #pragma unroll
        for (int r = 0; r < 4; ++r)
          ewt[(row + r) * EWS + col] = f2bf(acc[mi][r]);
      }
    }
    __syncthreads();
    // ---- consume phase: 16-lane group per edge, vectorized row reads
    float4 aA = *(const float4*)&att[nb * 128 + li * 8];
    float4 aB = *(const float4*)&att[nb * 128 + li * 8 + 4];
    #pragma unroll
    for (int e8 = 0; e8 < 8; ++e8){
      int r = grp * 8 + e8;
      uint4 qx = *(const uint4*)&XL [(size_t)soff8[e8] + nb * 128];
      uint4 qr = *(const uint4*)&XRb[(size_t)doff8[e8] + nb * 128];
      uint4 qe = *(const uint4*)&ewt[r * EWS + li * 8];
      float fx[8], fr8[8], fe[8];
      up8(qx, fx); up8(qr, fr8); up8(qe, fe);
      float s;
      s  = aA.x * lrelu(fx[0] + fr8[0] + fe[0]);
      s += aA.y * lrelu(fx[1] + fr8[1] + fe[1]);
      s += aA.z * lrelu(fx[2] + fr8[2] + fe[2]);
      s += aA.w * lrelu(fx[3] + fr8[3] + fe[3]);
      s += aB.x * lrelu(fx[4] + fr8[4] + fe[4]);
      s += aB.y * lrelu(fx[5] + fr8[5] + fe[5]);
      s += aB.z * lrelu(fx[6] + fr8[6] + fe[6]);
      s += aB.w * lrelu(fx[7] + fr8[7] + fe[7]);
      part[e8] += s;
    }
  }
  // reduce partials across the 16 lanes of each group
  #pragma unroll
  for (int e8 = 0; e8 < 8; ++e8){
    float v = part[e8];
    v += __shfl_xor(v, 1, 64);
    v += __shfl_xor(v, 2, 64);
    v += __shfl_xor(v, 4, 64);
    v += __shfl_xor(v, 8, 64);
    if (li == 0) logit[(size_t)half * eaug + base + grp * 8 + e8] = v;
  }
}

// ---- softmax + aggregation (one wave per dst node); logit = half0 + half1 --
// v11: 4-edge unroll (4x memory-level parallelism in the latency-bound edge
// loop); 2-wide max pass; blockIdx.y column-split for FO=1024.
template<int CHUNKS, int VEC, typename OutT>
__global__ __launch_bounds__(256) void k_agg(const unsigned short* __restrict__ XL,
    const float* __restrict__ logit, const int* __restrict__ csr_src,
    const int* __restrict__ row_start, const float* __restrict__ bc,
    OutT* __restrict__ out, int eaug, int FO){
  const int CW = CHUNKS * 64 * VEC;          // columns handled by this block
  int col0 = blockIdx.y * CW;
  int lane = threadIdx.x & 63;
  int wave = threadIdx.x >> 6;
  int n = blockIdx.x * 4 + wave;
  int rs = row_start[n], re = row_start[n + 1];
  int jj = lane * VEC;
  float m0 = -1e30f, m1 = -1e30f;            // 2-wide max pass (order-free)
  int im = rs;
  for (; im + 1 < re; im += 2){
    m0 = fmaxf(m0, logit[im] + logit[eaug + im]);
    m1 = fmaxf(m1, logit[im + 1] + logit[eaug + im + 1]);
  }
  if (im < re) m0 = fmaxf(m0, logit[im] + logit[eaug + im]);
  float m = fmaxf(m0, m1);
  float acc[CHUNKS][VEC];
  #pragma unroll
  for (int c = 0; c < CHUNKS; ++c)
    #pragma unroll
    for (int v = 0; v < VEC; ++v) acc[c][v] = 0.f;
  float den = 0.f;
  int i = rs;
  for (; i + 3 < re; i += 4){                // 4-edge unroll: 4 rows in flight
    int s0 = csr_src[i], s1 = csr_src[i + 1], s2 = csr_src[i + 2], s3 = csr_src[i + 3];
    float f0 = __expf(logit[i]     + logit[eaug + i]     - m);
    float f1 = __expf(logit[i + 1] + logit[eaug + i + 1] - m);
    float f2 = __expf(logit[i + 2] + logit[eaug + i + 2] - m);
    float f3 = __expf(logit[i + 3] + logit[eaug + i + 3] - m);
    const unsigned short* xp0 = XL + (size_t)s0 * FO + col0 + jj;
    const unsigned short* xp1 = XL + (size_t)s1 * FO + col0 + jj;
    const unsigned short* xp2 = XL + (size_t)s2 * FO + col0 + jj;
    const unsigned short* xp3 = XL + (size_t)s3 * FO + col0 + jj;
    den += (f0 + f1) + (f2 + f3);
    #pragma unroll
    for (int c = 0; c < CHUNKS; ++c){
      float xl0[VEC], xl1[VEC], xl2[VEC], xl3[VEC];
      if (VEC == 8){
        uint4 q0 = *(const uint4*)(xp0 + c * 64 * VEC);
        uint4 q1 = *(const uint4*)(xp1 + c * 64 * VEC);
        uint4 q2 = *(const uint4*)(xp2 + c * 64 * VEC);
        uint4 q3 = *(const uint4*)(xp3 + c * 64 * VEC);
        up8(q0, xl0); up8(q1, xl1); up8(q2, xl2); up8(q3, xl3);
      } else {
        ushort4 u0 = *(const ushort4*)(xp0 + c * 64 * VEC);
        ushort4 u1 = *(const ushort4*)(xp1 + c * 64 * VEC);
        ushort4 u2 = *(const ushort4*)(xp2 + c * 64 * VEC);
        ushort4 u3 = *(const ushort4*)(xp3 + c * 64 * VEC);
        xl0[0] = bf2f(u0.x); xl0[1] = bf2f(u0.y); xl0[2] = bf2f(u0.z); xl0[3] = bf2f(u0.w);
        xl1[0] = bf2f(u1.x); xl1[1] = bf2f(u1.y); xl1[2] = bf2f(u1.z); xl1[3] = bf2f(u1.w);
        xl2[0] = bf2f(u2.x); xl2[1] = bf2f(u2.y); xl2[2] = bf2f(u2.z); xl2[3] = bf2f(u2.w);
        xl3[0] = bf2f(u3.x); xl3[1] = bf2f(u3.y); xl3[2] = bf2f(u3.z); xl3[3] = bf2f(u3.w);
      }
      #pragma unroll
      for (int v = 0; v < VEC; ++v)
        acc[c][v] += (f0 * xl0[v] + f1 * xl1[v]) + (f2 * xl2[v] + f3 * xl3[v]);
    }
  }
  for (; i < re; ++i){                        // tail
    int s0 = csr_src[i];
    float f0 = __expf(logit[i] + logit[eaug + i] - m);
    const unsigned short* xp0 = XL + (size_t)s0 * FO + col0 + jj;
    den += f0;
    #pragma unroll
    for (int c = 0; c < CHUNKS; ++c){
      float xl0[VEC];
      if (VEC == 8){
        uint4 q0 = *(const uint4*)(xp0 + c * 64 * VEC);
        up8(q0, xl0);
      } else {
        ushort4 u0 = *(const ushort4*)(xp0 + c * 64 * VEC);
        xl0[0] = bf2f(u0.x); xl0[1] = bf2f(u0.y); xl0[2] = bf2f(u0.z); xl0[3] = bf2f(u0.w);
      }
      #pragma unroll
      for (int v = 0; v < VEC; ++v) acc[c][v] += f0 * xl0[v];
    }
  }
  float inv = 1.f / den;
  #pragma unroll
  for (int c = 0; c < CHUNKS; ++c){
    int cb = col0 + c * 64 * VEC + jj;
    #pragma unroll
    for (int v = 0; v < VEC; ++v){
      float b = bc[cb + v];
      float o = fmaxf(acc[c][v] * inv + b, 0.f);
      if (sizeof(OutT) == 4) ((float*)out)[(size_t)n * FO + cb + v] = o;
      else ((unsigned short*)out)[(size_t)n * FO + cb + v] = f2bf(o);
    }
  }
}

// ---- pooling stage A: partial sums (graph g, part p of 8) ------------------
__global__ void k_pool_part(const float* __restrict__ H, const int* __restrict__ batch,
                            float* __restrict__ partial, int N){
  __shared__ int se[2];
  int g = blockIdx.x, part = blockIdx.y;
  int t = threadIdx.x;
  if (t < 2){
    int target = g + t;
    int lo = 0, hi = N;
    while (lo < hi){ int mid = (lo + hi) >> 1; if (batch[mid] < target) lo = mid + 1; else hi = mid; }
    se[t] = lo;
  }
  __syncthreads();
  int s = se[0], e = se[1];
  int len = e - s;
  int p0 = s + (int)((long)len * part / 8);
  int p1 = s + (int)((long)len * (part + 1) / 8);
  float a = 0.f;
  for (int n = p0; n < p1; ++n) a += H[(size_t)n * 256 + t];
  partial[((size_t)g * 8 + part) * 256 + t] = a;
}

// ---- pooling stage B: combine partials + fc1 -------------------------------
__global__ void k_fc1b(const float* __restrict__ partial, const int* __restrict__ batch,
                       const float* __restrict__ w, const float* __restrict__ b,
                       float* __restrict__ z, int N){
  __shared__ float ps[256];
  __shared__ int se[2];
  int g = blockIdx.x;
  int t = threadIdx.x;
  if (t < 2){
    int target = g + t;
    int lo = 0, hi = N;
    while (lo < hi){ int mid = (lo + hi) >> 1; if (batch[mid] < target) lo = mid + 1; else hi = mid; }
    se[t] = lo;
  }
  float a = 0.f;
  #pragma unroll
  for (int p = 0; p < 8; ++p) a += partial[((size_t)g * 8 + p) * 256 + t];
  ps[t] = a;
  __syncthreads();
  if (t < 64){
    float acc = 0.f;
    for (int k = 0; k < 256; ++k) acc += ps[k] * w[k * 64 + t];
    z[g * 64 + t] = acc / fmaxf((float)(se[1] - se[0]), 1.f) + b[t];
  }
}

__global__ void k_head(const float* __restrict__ z, const float* __restrict__ bn_g,
                       const float* __restrict__ bn_b, const float* __restrict__ w2,
                       const float* __restrict__ b2, float* __restrict__ out){
  __shared__ float mu_s[64], is_s[64];
  int t = threadIdx.x;  // 128 threads
  if (t < 64){
    float mu = 0.f, m2 = 0.f;
    for (int g = 0; g < 128; ++g){ float v = z[g * 64 + t]; mu += v; m2 += v * v; }
    mu /= 128.f; m2 /= 128.f;
    float var = m2 - mu * mu;
    mu_s[t] = mu;
    is_s[t] = rsqrtf(var + 1e-5f);
  }
  __syncthreads();
  float o = b2[0];
  for (int j = 0; j < 64; ++j){
    float v = (z[t * 64 + j] - mu_s[j]) * is_s[j] * bn_g[j] + bn_b[j];
    o += fmaxf(v, 0.f) * w2[j];
  }
  out[t] = o;
}

extern "C" void kernel_launch(void* const* d_in, const int* in_sizes, int n_in,
                              void* d_out, int out_size, void* d_ws, size_t ws_size,
                              hipStream_t stream){
  const int N = 16384, E = 131072, Eaug = E + N, NG = 128;
  const float* x     = (const float*)d_in[0];
  const int*   ei    = (const int*)  d_in[1];
  const float* ea    = (const float*)d_in[2];
  const int*   batch = (const int*)  d_in[3];
  const float* Wl[3]  = {(const float*)d_in[4],  (const float*)d_in[11], (const float*)d_in[18]};
  const float* bl[3]  = {(const float*)d_in[5],  (const float*)d_in[12], (const float*)d_in[19]};
  const float* Wr[3]  = {(const float*)d_in[6],  (const float*)d_in[13], (const float*)d_in[20]};
  const float* br[3]  = {(const float*)d_in[7],  (const float*)d_in[14], (const float*)d_in[21]};
  const float* We[3]  = {(const float*)d_in[8],  (const float*)d_in[15], (const float*)d_in[22]};
  const float* att[3] = {(const float*)d_in[9],  (const float*)d_in[16], (const float*)d_in[23]};
  const float* bc[3]  = {(const float*)d_in[10], (const float*)d_in[17], (const float*)d_in[24]};
  const float* fc1_w = (const float*)d_in[25];
  const float* fc1_b = (const float*)d_in[26];
  const float* bn_g  = (const float*)d_in[27];
  const float* bn_b  = (const float*)d_in[28];
  const float* fc2_w = (const float*)d_in[29];
  const float* fc2_b = (const float*)d_in[30];
  float* out = (float*)d_out;

  char* wsb = (char*)d_ws;
  size_t off = 0;
  auto alloc = [&](size_t bytes) -> char* {
    char* p = wsb + off;
    off = (off + bytes + 255) & ~(size_t)255;
    return p;
  };
  int*   deg       = (int*)  alloc((size_t)N * 4);
  int*   fill      = (int*)  alloc((size_t)N * 4);
  int*   row_start = (int*)  alloc((size_t)(N + 1) * 4);
  int*   csr_src   = (int*)  alloc((size_t)Eaug * 4);
  int*   csr_eid   = (int*)  alloc((size_t)Eaug * 4);
  int*   csr_dst   = (int*)  alloc((size_t)Eaug * 4);
  float* logits    = (float*)alloc((size_t)2 * Eaug * 4);   // two tile-half partials
  unsigned short* ea_perm = (unsigned short*)alloc((size_t)Eaug * 32 * 2);
  unsigned short* XL   = (unsigned short*)alloc((size_t)N * 1024 * 2); // 32 MB
  unsigned short* XRb  = (unsigned short*)alloc((size_t)N * 1024 * 2); // 32 MB
  unsigned short* bufA = (unsigned short*)alloc((size_t)N * 1024 * 2); // 32 MB: Xb / L2-out
  unsigned short* bufB = (unsigned short*)alloc((size_t)N * 512 * 4);  // 32 MB: L1-out bf16 / L3-out fp32
  unsigned short* WtL  = (unsigned short*)alloc((size_t)1024 * 1024 * 2);
  unsigned short* WtR  = (unsigned short*)alloc((size_t)1024 * 1024 * 2);
  unsigned short* WeT  = (unsigned short*)alloc((size_t)1024 * 32 * 2);
  float* ppart     = (float*)alloc((size_t)NG * 8 * 256 * 4);
  float* zbuf      = (float*)alloc((size_t)NG * 64 * 4);

  hipMemsetAsync(deg, 0, (size_t)2 * N * 4, stream);  // deg + fill (adjacent)

  k_deg<<<E / 256, 256, 0, stream>>>(ei, deg, E);
  k_scan<<<1, 256, 0, stream>>>(deg, row_start, N);
  k_csr_build<<<(N + E) / 256, 256, 0, stream>>>(ei, row_start, fill, csr_src, csr_eid, csr_dst, N, E);
  k_eaprep<<<(N * 32 + Eaug * 8 + 255) / 256, 256, 0, stream>>>(ea, csr_eid, row_start, ea_perm, N, Eaug, E);
  k_cvt_bf16<<<(N * 256 / 4) / 256, 256, 0, stream>>>(x, bufA, N * 256 / 4);  // Xb in bufA

  const int fin[3] = {256, 512, 1024};
  const int fo[3]  = {512, 1024, 256};
  const unsigned short* Ain[3] = {bufA, bufB, bufA};

  for (int L = 0; L < 3; ++L){
    int FI = fin[L], FO = fo[L];
    k_transpose2_bf16<<<dim3(FO / 64, FI / 64, 2), 256, 0, stream>>>(Wl[L], Wr[L], WtL, WtR, FI, FO);
    k_transpose_we<<<(32 * FO + 255) / 256, 256, 0, stream>>>(We[L], WeT, FO);
    dim3 gg(N / 128, FO / 128, 2);
    k_mfma_gemm2<<<gg, 256, 0, stream>>>(Ain[L], WtL, WtR, bl[L], br[L], XL, XRb, FO, FI);

    // one logit pass (2 tile-half blocks per 128 slots) + one aggregation pass
    dim3 lg(Eaug / 128, 2);
    if (FO == 512){
      k_logit<4><<<lg, 256, 0, stream>>>(ea_perm, WeT, XL, XRb, csr_src, csr_dst, att[L], logits, Eaug);
      k_agg<1, 8, unsigned short><<<dim3(N / 4, 1), 256, 0, stream>>>(XL, logits, csr_src, row_start, bc[L], bufB, Eaug, 512);
    } else if (FO == 1024){
      k_logit<8><<<lg, 256, 0, stream>>>(ea_perm, WeT, XL, XRb, csr_src, csr_dst, att[L], logits, Eaug);
      k_agg<1, 8, unsigned short><<<dim3(N / 4, 2), 256, 0, stream>>>(XL, logits, csr_src, row_start, bc[L], bufA, Eaug, 1024);
    } else {
      k_logit<2><<<lg, 256, 0, stream>>>(ea_perm, WeT, XL, XRb, csr_src, csr_dst, att[L], logits, Eaug);
      k_agg<1, 4, float><<<dim3(N / 4, 1), 256, 0, stream>>>(XL, logits, csr_src, row_start, bc[L], (float*)bufB, Eaug, 256);
    }
  }

  k_pool_part<<<dim3(NG, 8), 256, 0, stream>>>((const float*)bufB, batch, ppart, N);
  k_fc1b<<<NG, 256, 0, stream>>>(ppart, batch, fc1_w, fc1_b, zbuf, N);
  k_head<<<1, 128, 0, stream>>>(zbuf, bn_g, bn_b, fc2_w, fc2_b, out);
}